// Round 7
// baseline (246.391 us; speedup 1.0000x reference)
//
#include <hip/hip_runtime.h>
#include <math.h>

#define D_    256
#define NE    512
#define NNODE 64
#define NHEAD 4
#define SLOPE 0.2f
#define BTN   65536

typedef __attribute__((ext_vector_type(4))) float f32x4;
typedef __attribute__((ext_vector_type(8))) short s16x8;
typedef unsigned short u16;

__device__ inline u16 f2bf(float x) {
    union { float f; unsigned u; } v; v.f = x;
    unsigned r = v.u + 0x7fff + ((v.u >> 16) & 1);
    return (u16)(r >> 16);
}
__device__ inline float bf2f(u16 b) {
    union { float f; unsigned u; } v; v.u = ((unsigned)b) << 16;
    return v.f;
}

#define GLD16(g, l) __builtin_amdgcn_global_load_lds( \
    (const __attribute__((address_space(1))) void*)(g), \
    (__attribute__((address_space(3))) void*)(l), 16, 0, 0)

// ---------------------------------------------------------------------------
// Parallel deterministic CSR build + log(A0+eps). One block, 512 threads.
// ---------------------------------------------------------------------------
__global__ __launch_bounds__(512) void build_csr(const int* __restrict__ src,
    const int* __restrict__ dst, const float* __restrict__ A0,
    int* __restrict__ csr_off, int* __restrict__ csr_eid, float* __restrict__ logA0)
{
    __shared__ int sS[NE];
    __shared__ int sCnt[NNODE];
    __shared__ int sOf[NNODE + 1];
    const int t = threadIdx.x;
    sS[t] = src[t];
    __syncthreads();
    if (t < NNODE) {
        int c = 0;
        for (int e = 0; e < NE; ++e) c += (sS[e] == t);
        sCnt[t] = c;
    }
    __syncthreads();
    if (t == 0) {
        int run = 0;
        for (int n = 0; n < NNODE; ++n) { sOf[n] = run; run += sCnt[n]; }
        sOf[NNODE] = run;
    }
    __syncthreads();
    {
        int s = sS[t];
        int rank = 0;
        for (int e = 0; e < NE; ++e) rank += (int)((sS[e] == s) && (e < t));
        csr_eid[sOf[s] + rank] = t;                 // stable order within segment
        logA0[t] = logf(A0[s * NNODE + dst[t]] + 1e-8f);
    }
    if (t <= NNODE) csr_off[t] = sOf[t];
}

// ---------------------------------------------------------------------------
// fp32 -> split bf16 (hi + lo), grid-stride over float4s.
// ---------------------------------------------------------------------------
__global__ __launch_bounds__(256) void prep_split(const float* __restrict__ s,
    u16* __restrict__ h, u16* __restrict__ l, int n4)
{
    for (int i = blockIdx.x * 256 + threadIdx.x; i < n4; i += gridDim.x * 256) {
        float4 v = ((const float4*)s)[i];
        u16 h0 = f2bf(v.x), h1 = f2bf(v.y), h2 = f2bf(v.z), h3 = f2bf(v.w);
        ((ushort4*)h)[i] = make_ushort4(h0, h1, h2, h3);
        ((ushort4*)l)[i] = make_ushort4(f2bf(v.x - bf2f(h0)), f2bf(v.y - bf2f(h1)),
                                        f2bf(v.z - bf2f(h2)), f2bf(v.w - bf2f(h3)));
    }
}

// ---------------------------------------------------------------------------
// Split-bf16 MFMA GEMM. FULL: 3-pass (hh+hl+lh); else 1-pass bf16.
// OMODE 0: fp32 row-major C.  OMODE 2: bf16, per-bt transposed (V^T) with
// node-chunk XOR swizzle baked in: off = bt*16384 + n*64 + ((m&63)^((n&7)<<3)).
// ---------------------------------------------------------------------------
template<bool FULL, int OMODE>
__global__ __launch_bounds__(256) void gemm_bf16s(const u16* __restrict__ Ah,
    const u16* __restrict__ Al, const u16* __restrict__ Bh, const u16* __restrict__ Bl,
    void* __restrict__ Cout)
{
    __shared__ u16 sAh[4096], sBh[4096];                 // [128][32], linear
    __shared__ u16 sAl[FULL ? 4096 : 16], sBl[FULL ? 4096 : 16];
    const int t = threadIdx.x, lane = t & 63, wave = t >> 6;
    const int wm = wave >> 1, wn = wave & 1;
    const int bid = blockIdx.x;
    const int swz = (bid & 7) * 128 + (bid >> 3);        // XCD-contiguous
    const int m0 = (swz >> 1) * 128, n0 = (swz & 1) * 128;
    const int fr = lane & 15, kq = (lane >> 4) * 8;

    f32x4 acc[4][4];
    #pragma unroll
    for (int i = 0; i < 4; ++i)
        #pragma unroll
        for (int j = 0; j < 4; ++j) acc[i][j] = 0.f;

    for (int k0 = 0; k0 < D_; k0 += 32) {
        #pragma unroll
        for (int s = 0; s < 2; ++s) {
            const int cb = (s * 4 + wave) * 64;
            const int c  = cb + lane;
            const int row = c >> 2, ks = (c & 3) * 8;
            const size_t ga = (size_t)(m0 + row) * D_ + k0 + ks;
            const size_t gb = (size_t)(n0 + row) * D_ + k0 + ks;
            GLD16(Ah + ga, sAh + cb * 8);
            GLD16(Bh + gb, sBh + cb * 8);
            if (FULL) {
                GLD16(Al + ga, sAl + cb * 8);
                GLD16(Bl + gb, sBl + cb * 8);
            }
        }
        __syncthreads();

        s16x8 fah[4], fal[4];
        #pragma unroll
        for (int mi = 0; mi < 4; ++mi) {
            fah[mi] = *(const s16x8*)(sAh + (wm * 64 + mi * 16 + fr) * 32 + kq);
            if (FULL) fal[mi] = *(const s16x8*)(sAl + (wm * 64 + mi * 16 + fr) * 32 + kq);
        }
        #pragma unroll
        for (int ni = 0; ni < 4; ++ni) {
            s16x8 fbh = *(const s16x8*)(sBh + (wn * 64 + ni * 16 + fr) * 32 + kq);
            s16x8 fbl;
            if (FULL) fbl = *(const s16x8*)(sBl + (wn * 64 + ni * 16 + fr) * 32 + kq);
            #pragma unroll
            for (int mi = 0; mi < 4; ++mi) {
                acc[mi][ni] = __builtin_amdgcn_mfma_f32_16x16x32_bf16(fah[mi], fbh, acc[mi][ni], 0, 0, 0);
                if (FULL) {
                    acc[mi][ni] = __builtin_amdgcn_mfma_f32_16x16x32_bf16(fah[mi], fbl, acc[mi][ni], 0, 0, 0);
                    acc[mi][ni] = __builtin_amdgcn_mfma_f32_16x16x32_bf16(fal[mi], fbh, acc[mi][ni], 0, 0, 0);
                }
            }
        }
        __syncthreads();
    }

    const int fq = (lane >> 4) * 4;   // C/D: col = lane&15, row = (lane>>4)*4 + reg
    #pragma unroll
    for (int mi = 0; mi < 4; ++mi)
        #pragma unroll
        for (int ni = 0; ni < 4; ++ni)
            #pragma unroll
            for (int r = 0; r < 4; ++r) {
                int m = m0 + wm * 64 + mi * 16 + fq + r;
                int n = n0 + wn * 64 + ni * 16 + fr;
                if (OMODE == 0) {
                    ((float*)Cout)[(size_t)m * D_ + n] = acc[mi][ni][r];
                } else {
                    size_t off = (size_t)(m >> 6) * 16384 + (size_t)n * 64
                               + ((m & 63) ^ ((n & 7) << 3));
                    ((u16*)Cout)[off] = f2bf(acc[mi][ni][r]);
                }
            }
}

// ---------------------------------------------------------------------------
// Fused edge scores + segment softmax + P-matrix build + MFMA aggregation.
// One block per (bt, head). Y^T = V^T · P^T via mfma(A=V^T, B=P) (= A·B^T).
// LDS 39.4 KB -> 4 blocks/CU.
// ---------------------------------------------------------------------------
__global__ __launch_bounds__(256) void fused_edge_agg(
    const float* __restrict__ Xq, const u16* __restrict__ Xvt,
    const int* __restrict__ gsrc, const int* __restrict__ gdst,
    const float* __restrict__ a, const float* __restrict__ logA0,
    const int* __restrict__ csr_off, const int* __restrict__ csr_eid,
    u16* __restrict__ Yh, u16* __restrict__ Yl)
{
    __shared__ float sQ[NNODE * 64];   // 16 KB fp32, linear
    __shared__ u16   sVt[4096];        // 8 KB  V^T [dim][node], chunk^=(dim&7)
    __shared__ u16   sP[4096];         // 8 KB  P [src][dst],    chunk^=(src&7)
    __shared__ float sE[NE];           // 2 KB  scores -> exp
    __shared__ int   sPack[NE];        // 2 KB  (src<<8)|dst
    __shared__ int   sEid[NE];         // 2 KB
    __shared__ float sDen[NNODE];
    __shared__ int   sOff[NNODE + 1];

    const int t = threadIdx.x, lane = t & 63, wave = t >> 6;
    const int grp = t >> 4, lg = t & 15;
    const int fr = lane & 15;
    const int bt = blockIdx.x >> 2, h = blockIdx.x & 3;

    // ---- stage: Q fp32 linear; V^T slice is contiguous 8KB (pre-swizzled) ----
    const float* gq = Xq + (size_t)bt * (NNODE * D_) + h * 64;
    #pragma unroll
    for (int r = 0; r < 4; ++r) {
        int id = r * 256 + t, row = id >> 4, c4 = id & 15;
        GLD16(gq + (size_t)row * D_ + c4 * 4, (char*)sQ + id * 16);
    }
    const u16* gv = Xvt + (size_t)bt * (NNODE * D_) + h * 4096;
    #pragma unroll
    for (int r = 0; r < 2; ++r) {
        int id = r * 256 + t;
        GLD16(gv + id * 8, (char*)sVt + id * 16);
    }
    sPack[t]       = (gsrc[t] << 8)       | gdst[t];
    sPack[t + 256] = (gsrc[t + 256] << 8) | gdst[t + 256];
    sEid[t] = csr_eid[t]; sEid[t + 256] = csr_eid[t + 256];
    if (t <= NNODE) sOff[t] = csr_off[t];
    #pragma unroll
    for (int r = 0; r < 8; ++r) ((unsigned*)sP)[r * 256 + t] = 0;   // zero P
    const float4 areg = *(const float4*)&a[h * 64 + lg * 4];
    __syncthreads();

    // ---- edge scores (round-4 linear form): group of 16 lanes per edge ----
    for (int it = 0; it < 32; ++it) {
        int e = grp * 32 + it;
        int pk = sPack[e];
        int s_ = pk >> 8, d_ = pk & 255;
        float4 q = ((const float4*)sQ)[s_ * 16 + lg];
        float4 k = ((const float4*)sQ)[d_ * 16 + lg];
        float x0 = q.x + k.x, x1 = q.y + k.y, x2 = q.z + k.z, x3 = q.w + k.w;
        x0 = x0 > 0.f ? x0 : SLOPE * x0;
        x1 = x1 > 0.f ? x1 : SLOPE * x1;
        x2 = x2 > 0.f ? x2 : SLOPE * x2;
        x3 = x3 > 0.f ? x3 : SLOPE * x3;
        float p = x0 * areg.x + x1 * areg.y + x2 * areg.z + x3 * areg.w;
        p += __shfl_xor(p, 1);
        p += __shfl_xor(p, 2);
        p += __shfl_xor(p, 4);
        p += __shfl_xor(p, 8);
        if (lg == 0) sE[e] = p + logA0[e];    // logA0 is L2-hot (2 KB)
    }
    __syncthreads();

    // ---- segment softmax: 4 threads per node (quad in same wave) ----
    {
        int n = t >> 2, q = t & 3;
        int o0 = sOff[n], o1 = sOff[n + 1];
        float m = -INFINITY;
        for (int i = o0 + q; i < o1; i += 4) m = fmaxf(m, sE[sEid[i]]);
        m = fmaxf(m, __shfl_xor(m, 1));
        m = fmaxf(m, __shfl_xor(m, 2));
        float den = 0.f;
        for (int i = o0 + q; i < o1; i += 4) {
            int e = sEid[i];
            float w = __expf(sE[e] - m);
            den += w;
            sE[e] = w;
        }
        den += __shfl_xor(den, 1);
        den += __shfl_xor(den, 2);
        if (q == 0) sDen[n] = (o1 > o0) ? 1.f / den : 0.f;
    }
    __syncthreads();

    // ---- build P[src][dst] (bf16, swizzled cols): row-owner scatter ----
    if (t < NNODE) {
        int o0 = sOff[t], o1 = sOff[t + 1];
        float inv = sDen[t];
        int rb = t * 64, sw = (t & 7) << 3;
        for (int i = o0; i < o1; ++i) {
            int e = sEid[i];
            int adr = rb + (((sPack[e] & 255)) ^ sw);
            sP[adr] = f2bf(bf2f(sP[adr]) + sE[e] * inv);   // duplicate-safe (serial)
        }
    }
    __syncthreads();

    // ---- Y^T = V^T · P^T : wave owns 16 src nodes; 8 MFMAs ----
    f32x4 acc[4];
    #pragma unroll
    for (int i = 0; i < 4; ++i) acc[i] = 0.f;
    const int srow = wave * 16 + fr;
    const int qtr  = lane >> 4;
    #pragma unroll
    for (int kk = 0; kk < 2; ++kk) {
        int g = kk * 4 + qtr;
        s16x8 fb = *(const s16x8*)&sP[srow * 64 + ((g ^ (srow & 7)) << 3)];
        #pragma unroll
        for (int mi = 0; mi < 4; ++mi) {
            int arow = mi * 16 + fr;
            s16x8 fa = *(const s16x8*)&sVt[arow * 64 + ((g ^ (arow & 7)) << 3)];
            acc[mi] = __builtin_amdgcn_mfma_f32_16x16x32_bf16(fa, fb, acc[mi], 0, 0, 0);
        }
    }

    // ---- store: C[m=dim][n=src]; col=lane&15 -> node, row=(lane>>4)*4+r -> dim
    const int node = wave * 16 + fr;
    const int fq = qtr * 4;
    u16* yh = Yh + ((size_t)bt * NNODE + node) * D_ + h * 64;
    u16* yl = Yl + ((size_t)bt * NNODE + node) * D_ + h * 64;
    #pragma unroll
    for (int mi = 0; mi < 4; ++mi) {
        float ax = acc[mi][0], ay = acc[mi][1], az = acc[mi][2], aw = acc[mi][3];
        u16 h0 = f2bf(ax), h1 = f2bf(ay), h2 = f2bf(az), h3 = f2bf(aw);
        *(ushort4*)&yh[mi * 16 + fq] = make_ushort4(h0, h1, h2, h3);
        *(ushort4*)&yl[mi * 16 + fq] =
            make_ushort4(f2bf(ax - bf2f(h0)), f2bf(ay - bf2f(h1)),
                         f2bf(az - bf2f(h2)), f2bf(aw - bf2f(h3)));
    }
}

// ---------------------------------------------------------------------------
extern "C" void kernel_launch(void* const* d_in, const int* in_sizes, int n_in,
                              void* d_out, int out_size, void* d_ws, size_t ws_size,
                              hipStream_t stream)
{
    const float* H     = (const float*)d_in[0];
    const float* W_lin = (const float*)d_in[1];
    const float* W_val = (const float*)d_in[2];
    const float* a     = (const float*)d_in[3];
    const float* W_out = (const float*)d_in[4];
    const float* A0    = (const float*)d_in[5];
    const int*   src   = (const int*)d_in[6];
    const int*   dst   = (const int*)d_in[7];

    const size_t nX = (size_t)BTN * D_;              // 16777216 elems
    // ws: Hh | Hl | Xq(fp32)  == 134217728 B exactly
    u16*   Hh = (u16*)d_ws;
    u16*   Hl = Hh + nX;
    float* Xq = (float*)(Hl + nX);
    u16*   Yh = Hh;                                  // alias: H dead after GEMM2
    u16*   Yl = Hl;
    u16*   Wouth = (u16*)Xq;                         // alias: Xq dead after fused
    u16*   Woutl = Wouth + D_ * D_;
    if (ws_size < (size_t)134217728) return;

    // d_out scratch until GEMM3: Xvt bf16 [0,33.5MB) ; lists/W-splits at +40MB
    u16*   Xvt = (u16*)d_out;
    char*  sc2 = (char*)d_out + (size_t)40 * 1024 * 1024;
    float* logA0   = (float*)sc2;                    // 2 KB
    int*   csr_off = (int*)(sc2 + 4096);
    int*   csr_eid = (int*)(sc2 + 8192);
    u16*   Wlh = (u16*)(sc2 + 16384);                // 128 KB each
    u16*   Wll = Wlh + D_ * D_;
    u16*   Wvh = Wll + D_ * D_;
    u16*   Wvl = Wvh + D_ * D_;

    build_csr<<<1, 512, 0, stream>>>(src, dst, A0, csr_off, csr_eid, logA0);
    prep_split<<<4096, 256, 0, stream>>>(H, Hh, Hl, (int)(nX / 4));
    prep_split<<<64, 256, 0, stream>>>(W_lin, Wlh, Wll, D_ * D_ / 4);
    prep_split<<<64, 256, 0, stream>>>(W_val, Wvh, Wvl, D_ * D_ / 4);

    gemm_bf16s<true,  0><<<1024, 256, 0, stream>>>(Hh, Hl, Wlh, Wll, Xq);
    gemm_bf16s<false, 2><<<1024, 256, 0, stream>>>(Hh, Hl, Wvh, Wvl, Xvt);

    fused_edge_agg<<<4096, 256, 0, stream>>>(Xq, Xvt, src, dst, a, logA0,
                                             csr_off, csr_eid, Yh, Yl);

    prep_split<<<64, 256, 0, stream>>>(W_out, Wouth, Woutl, D_ * D_ / 4);
    gemm_bf16s<true,  0><<<1024, 256, 0, stream>>>(Yh, Yl, Wouth, Woutl, (float*)d_out);
}

// Round 8
// 203.407 us; speedup vs baseline: 1.2113x; 1.2113x over previous
//
#include <hip/hip_runtime.h>
#include <math.h>

#define D_    256
#define NE    512
#define NNODE 64
#define NHEAD 4
#define SLOPE 0.2f
#define BTN   65536

typedef __attribute__((ext_vector_type(4))) float f32x4;
typedef __attribute__((ext_vector_type(8))) short s16x8;
typedef unsigned short u16;

__device__ inline u16 f2bf(float x) {
    union { float f; unsigned u; } v; v.f = x;
    unsigned r = v.u + 0x7fff + ((v.u >> 16) & 1);
    return (u16)(r >> 16);
}
__device__ inline float bf2f(u16 b) {
    union { float f; unsigned u; } v; v.u = ((unsigned)b) << 16;
    return v.f;
}

#define GLD16(g, l) __builtin_amdgcn_global_load_lds( \
    (const __attribute__((address_space(1))) void*)(g), \
    (__attribute__((address_space(3))) void*)(l), 16, 0, 0)

// ---------------------------------------------------------------------------
// Per-edge log(A0[src,dst]+eps). One block, 512 threads.
// ---------------------------------------------------------------------------
__global__ __launch_bounds__(512) void build_log(const int* __restrict__ src,
    const int* __restrict__ dst, const float* __restrict__ A0,
    float* __restrict__ logA0)
{
    const int t = threadIdx.x;
    logA0[t] = logf(A0[src[t] * NNODE + dst[t]] + 1e-8f);
}

// ---------------------------------------------------------------------------
// fp32 -> split bf16 (hi + lo), grid-stride over float4s.
// ---------------------------------------------------------------------------
__global__ __launch_bounds__(256) void prep_split(const float* __restrict__ s,
    u16* __restrict__ h, u16* __restrict__ l, int n4)
{
    for (int i = blockIdx.x * 256 + threadIdx.x; i < n4; i += gridDim.x * 256) {
        float4 v = ((const float4*)s)[i];
        u16 h0 = f2bf(v.x), h1 = f2bf(v.y), h2 = f2bf(v.z), h3 = f2bf(v.w);
        ((ushort4*)h)[i] = make_ushort4(h0, h1, h2, h3);
        ((ushort4*)l)[i] = make_ushort4(f2bf(v.x - bf2f(h0)), f2bf(v.y - bf2f(h1)),
                                        f2bf(v.z - bf2f(h2)), f2bf(v.w - bf2f(h3)));
    }
}

// ---------------------------------------------------------------------------
// Split-bf16 MFMA GEMM. FULL: 3-pass (hh+hl+lh); else 1-pass bf16.
// OMODE 0: fp32 row-major C.
// OMODE 2: bf16 V^T per (bt,h): each wave's 64x64 quadrant == one slice;
//          transpose via 8KB LDS (swizzled), then one coalesced 8KB store.
//          Slice layout: [dim][node] with 16B-chunk ^= (dim&7).
// ---------------------------------------------------------------------------
template<bool FULL, int OMODE>
__global__ __launch_bounds__(256) void gemm_bf16s(const u16* __restrict__ Ah,
    const u16* __restrict__ Al, const u16* __restrict__ Bh, const u16* __restrict__ Bl,
    void* __restrict__ Cout)
{
    __shared__ u16 sAh[4096], sBh[4096];                 // [128][32], linear
    __shared__ u16 sAl[FULL ? 4096 : 16], sBl[FULL ? 4096 : 16];
    __shared__ u16 sT[OMODE == 2 ? 16384 : 16];          // 4 waves x 8KB transpose
    const int t = threadIdx.x, lane = t & 63, wave = t >> 6;
    const int wm = wave >> 1, wn = wave & 1;
    const int bid = blockIdx.x;
    const int swz = (bid & 7) * 128 + (bid >> 3);        // XCD-contiguous
    const int m0 = (swz >> 1) * 128, n0 = (swz & 1) * 128;
    const int fr = lane & 15, kq = (lane >> 4) * 8;

    f32x4 acc[4][4];
    #pragma unroll
    for (int i = 0; i < 4; ++i)
        #pragma unroll
        for (int j = 0; j < 4; ++j) acc[i][j] = 0.f;

    for (int k0 = 0; k0 < D_; k0 += 32) {
        #pragma unroll
        for (int s = 0; s < 2; ++s) {
            const int cb = (s * 4 + wave) * 64;
            const int c  = cb + lane;
            const int row = c >> 2, ks = (c & 3) * 8;
            const size_t ga = (size_t)(m0 + row) * D_ + k0 + ks;
            const size_t gb = (size_t)(n0 + row) * D_ + k0 + ks;
            GLD16(Ah + ga, sAh + cb * 8);
            GLD16(Bh + gb, sBh + cb * 8);
            if (FULL) {
                GLD16(Al + ga, sAl + cb * 8);
                GLD16(Bl + gb, sBl + cb * 8);
            }
        }
        __syncthreads();

        s16x8 fah[4], fal[4];
        #pragma unroll
        for (int mi = 0; mi < 4; ++mi) {
            fah[mi] = *(const s16x8*)(sAh + (wm * 64 + mi * 16 + fr) * 32 + kq);
            if (FULL) fal[mi] = *(const s16x8*)(sAl + (wm * 64 + mi * 16 + fr) * 32 + kq);
        }
        #pragma unroll
        for (int ni = 0; ni < 4; ++ni) {
            s16x8 fbh = *(const s16x8*)(sBh + (wn * 64 + ni * 16 + fr) * 32 + kq);
            s16x8 fbl;
            if (FULL) fbl = *(const s16x8*)(sBl + (wn * 64 + ni * 16 + fr) * 32 + kq);
            #pragma unroll
            for (int mi = 0; mi < 4; ++mi) {
                acc[mi][ni] = __builtin_amdgcn_mfma_f32_16x16x32_bf16(fah[mi], fbh, acc[mi][ni], 0, 0, 0);
                if (FULL) {
                    acc[mi][ni] = __builtin_amdgcn_mfma_f32_16x16x32_bf16(fah[mi], fbl, acc[mi][ni], 0, 0, 0);
                    acc[mi][ni] = __builtin_amdgcn_mfma_f32_16x16x32_bf16(fal[mi], fbh, acc[mi][ni], 0, 0, 0);
                }
            }
        }
        __syncthreads();
    }

    const int fq = (lane >> 4) * 4;   // C/D: col = lane&15, row = (lane>>4)*4 + reg
    if (OMODE == 0) {
        #pragma unroll
        for (int mi = 0; mi < 4; ++mi)
            #pragma unroll
            for (int ni = 0; ni < 4; ++ni)
                #pragma unroll
                for (int r = 0; r < 4; ++r) {
                    int m = m0 + wm * 64 + mi * 16 + fq + r;
                    int n = n0 + wn * 64 + ni * 16 + fr;
                    ((float*)Cout)[(size_t)m * D_ + n] = acc[mi][ni][r];
                }
    } else {
        // wave quadrant = 64 nodes (rows) x 64 dims (cols) = one (bt,h) slice
        u16* wT = sT + wave * 4096;
        #pragma unroll
        for (int mi = 0; mi < 4; ++mi)
            #pragma unroll
            for (int ni = 0; ni < 4; ++ni) {
                int node0 = mi * 16 + fq;          // r = 0..3 consecutive nodes
                int dim   = ni * 16 + fr;
                ushort4 v = make_ushort4(f2bf(acc[mi][ni][0]), f2bf(acc[mi][ni][1]),
                                         f2bf(acc[mi][ni][2]), f2bf(acc[mi][ni][3]));
                *(ushort4*)&wT[dim * 64 + (((node0 >> 3) ^ (dim & 7)) << 3) + (node0 & 7)] = v;
            }
        __syncthreads();
        const int btq = (m0 >> 6) + wm;
        const int hq  = (n0 >> 6) + wn;
        u16* gvt = (u16*)Cout + ((size_t)btq * NHEAD + hq) * 4096;
        #pragma unroll
        for (int r = 0; r < 8; ++r) {
            s16x8 v = *(const s16x8*)&wT[r * 512 + lane * 8];
            *(s16x8*)&gvt[r * 512 + lane * 8] = v;
        }
    }
}

// ---------------------------------------------------------------------------
// Fused edge scores + segment softmax + aggregation, one block per (bt, head).
// All segment ops are edge-parallel via LDS atomics (no CSR, no serial loops):
//   scores -> atomicMax(sM[src])  ->  atomicAdd(sDen[src], exp)  ->
//   atomicAdd(P_f32[src][dst], w) ->  normalize+bf16 P  ->  MFMA Y^T = Vt·P^T.
// P_f32 aliases dead sQ. LDS ~36.5KB -> 4 blocks/CU.
// ---------------------------------------------------------------------------
__global__ __launch_bounds__(256) void fused_edge_agg(
    const float* __restrict__ Xq, const u16* __restrict__ Xvt,
    const int* __restrict__ gsrc, const int* __restrict__ gdst,
    const float* __restrict__ a, const float* __restrict__ logA0,
    u16* __restrict__ Yh)
{
    __shared__ float    sQP[4096];     // 16 KB: Q [node][16xf4], then P f32 [src][dst]
    __shared__ u16      sVt[4096];     // 8 KB  V^T [dim][node], chunk ^= (dim&7)
    __shared__ u16      sPb[4096];     // 8 KB  P bf16 [src][dst], chunk ^= (src&7)
    __shared__ float    sE[NE];        // raw logits -> exp weights
    __shared__ int      sPack[NE];     // (src<<8)|dst
    __shared__ unsigned sM[NNODE];     // segment max (monotonic uint key)
    __shared__ float    sDen[NNODE];

    const int t = threadIdx.x, lane = t & 63, wave = t >> 6;
    const int grp = t >> 4, lg = t & 15, g3 = grp & 3;
    const int bt = blockIdx.x >> 2, h = blockIdx.x & 3;

    // ---- stage ----
    const float* gq = Xq + (size_t)bt * (NNODE * D_) + h * 64;
    #pragma unroll
    for (int r = 0; r < 4; ++r) {
        int id = r * 256 + t, row = id >> 4, c4 = id & 15;
        GLD16(gq + (size_t)row * D_ + c4 * 4, (char*)sQP + id * 16);
    }
    const u16* gv = Xvt + ((size_t)bt * NHEAD + h) * 4096;
    #pragma unroll
    for (int r = 0; r < 2; ++r) {
        int id = r * 256 + t;
        GLD16(gv + id * 8, (char*)sVt + id * 16);
    }
    sPack[t]       = (gsrc[t] << 8)       | gdst[t];
    sPack[t + 256] = (gsrc[t + 256] << 8) | gdst[t + 256];
    if (t < NNODE) { sM[t] = 0u; sDen[t] = 0.f; }
    const int ci = lg ^ g3;                       // bank-rotated chunk index
    const float4 areg = *(const float4*)&a[h * 64 + ci * 4];
    __syncthreads();

    // ---- scores + segment max (group of 16 lanes per edge) ----
    for (int it = 0; it < 32; ++it) {
        int e = grp * 32 + it;
        int pk = sPack[e];
        int s_ = pk >> 8, d_ = pk & 255;
        float4 q = ((const float4*)sQP)[s_ * 16 + ci];
        float4 k = ((const float4*)sQP)[d_ * 16 + ci];
        float x0 = q.x + k.x, x1 = q.y + k.y, x2 = q.z + k.z, x3 = q.w + k.w;
        x0 = x0 > 0.f ? x0 : SLOPE * x0;
        x1 = x1 > 0.f ? x1 : SLOPE * x1;
        x2 = x2 > 0.f ? x2 : SLOPE * x2;
        x3 = x3 > 0.f ? x3 : SLOPE * x3;
        float p = x0 * areg.x + x1 * areg.y + x2 * areg.z + x3 * areg.w;
        p += __shfl_xor(p, 1);
        p += __shfl_xor(p, 2);
        p += __shfl_xor(p, 4);
        p += __shfl_xor(p, 8);
        if (lg == 0) {
            float ev = p + logA0[e];
            sE[e] = ev;
            unsigned u = __float_as_uint(ev);
            unsigned key = (u & 0x80000000u) ? ~u : (u | 0x80000000u);
            atomicMax(&sM[s_], key);
        }
    }
    __syncthreads();

    // ---- zero P (over dead Q) + edge-parallel denominator ----
    #pragma unroll
    for (int i = 0; i < 4; ++i)
        ((float4*)sQP)[t + i * 256] = make_float4(0.f, 0.f, 0.f, 0.f);
    #pragma unroll
    for (int i = 0; i < 2; ++i) {
        int e = t + i * 256;
        int s_ = sPack[e] >> 8;
        unsigned key = sM[s_];
        unsigned um = (key & 0x80000000u) ? (key ^ 0x80000000u) : ~key;
        float m = __uint_as_float(um);
        float w = __expf(sE[e] - m);
        sE[e] = w;
        atomicAdd(&sDen[s_], w);
    }
    __syncthreads();

    // ---- edge-parallel P scatter (unnormalized; duplicates via atomics) ----
    #pragma unroll
    for (int i = 0; i < 2; ++i) {
        int e = t + i * 256;
        int pk = sPack[e];
        atomicAdd(&sQP[(pk >> 8) * 64 + (pk & 255)], sE[e]);
    }
    __syncthreads();

    // ---- normalize + convert P -> bf16 swizzled; thread t: row t>>2, 16 cols ----
    {
        int s_ = t >> 2, c0 = (t & 3) * 16;
        float den = sDen[s_];
        float inv = den > 0.f ? 1.f / den : 0.f;
        #pragma unroll
        for (int half = 0; half < 2; ++half) {
            int c = c0 + half * 8;
            float4 v0 = *(const float4*)&sQP[s_ * 64 + c];
            float4 v1 = *(const float4*)&sQP[s_ * 64 + c + 4];
            ushort4 o0 = make_ushort4(f2bf(v0.x * inv), f2bf(v0.y * inv),
                                      f2bf(v0.z * inv), f2bf(v0.w * inv));
            ushort4 o1 = make_ushort4(f2bf(v1.x * inv), f2bf(v1.y * inv),
                                      f2bf(v1.z * inv), f2bf(v1.w * inv));
            int base = s_ * 64 + (((c >> 3) ^ (s_ & 7)) << 3);
            *(ushort4*)&sPb[base]     = o0;
            *(ushort4*)&sPb[base + 4] = o1;
        }
    }
    __syncthreads();

    // ---- Y^T = V^T · P^T : wave owns 16 src nodes; 8 MFMAs ----
    f32x4 acc[4];
    #pragma unroll
    for (int i = 0; i < 4; ++i) acc[i] = 0.f;
    const int fr = lane & 15;
    const int srow = wave * 16 + fr;
    const int qtr  = lane >> 4;
    #pragma unroll
    for (int kk = 0; kk < 2; ++kk) {
        int g = kk * 4 + qtr;
        s16x8 fb = *(const s16x8*)&sPb[srow * 64 + ((g ^ (srow & 7)) << 3)];
        #pragma unroll
        for (int mi = 0; mi < 4; ++mi) {
            int arow = mi * 16 + fr;
            s16x8 fa = *(const s16x8*)&sVt[arow * 64 + ((g ^ (arow & 7)) << 3)];
            acc[mi] = __builtin_amdgcn_mfma_f32_16x16x32_bf16(fa, fb, acc[mi], 0, 0, 0);
        }
    }

    // ---- store: C[m=dim][n=src]; col=lane&15 -> node, row=(lane>>4)*4+r -> dim
    const int node = wave * 16 + fr;
    const int fq = qtr * 4;
    u16* yh = Yh + ((size_t)bt * NNODE + node) * D_ + h * 64;
    #pragma unroll
    for (int mi = 0; mi < 4; ++mi) {
        ushort4 v = make_ushort4(f2bf(acc[mi][0]), f2bf(acc[mi][1]),
                                 f2bf(acc[mi][2]), f2bf(acc[mi][3]));
        *(ushort4*)&yh[mi * 16 + fq] = v;
    }
}

// ---------------------------------------------------------------------------
extern "C" void kernel_launch(void* const* d_in, const int* in_sizes, int n_in,
                              void* d_out, int out_size, void* d_ws, size_t ws_size,
                              hipStream_t stream)
{
    const float* H     = (const float*)d_in[0];
    const float* W_lin = (const float*)d_in[1];
    const float* W_val = (const float*)d_in[2];
    const float* a     = (const float*)d_in[3];
    const float* W_out = (const float*)d_in[4];
    const float* A0    = (const float*)d_in[5];
    const int*   src   = (const int*)d_in[6];
    const int*   dst   = (const int*)d_in[7];

    const size_t nX = (size_t)BTN * D_;              // 16777216 elems
    // ws: Hh | Hl | Xq(fp32)  == 134217728 B exactly
    u16*   Hh = (u16*)d_ws;
    u16*   Hl = Hh + nX;
    float* Xq = (float*)(Hl + nX);
    u16*   Yh = Hh;                                  // alias: H dead after GEMM2
    u16*   Wouth = (u16*)Xq;                         // alias: Xq dead after fused
    u16*   Woutl = Wouth + D_ * D_;
    if (ws_size < (size_t)134217728) return;

    // d_out scratch until GEMM3: Xvt bf16 [0,33.5MB) ; logA0/W-splits at +40MB
    u16*   Xvt = (u16*)d_out;
    char*  sc2 = (char*)d_out + (size_t)40 * 1024 * 1024;
    float* logA0 = (float*)sc2;                      // 2 KB
    u16*   Wlh = (u16*)(sc2 + 16384);                // 128 KB each
    u16*   Wll = Wlh + D_ * D_;
    u16*   Wvh = Wll + D_ * D_;
    u16*   Wvl = Wvh + D_ * D_;

    build_log<<<1, 512, 0, stream>>>(src, dst, A0, logA0);
    prep_split<<<4096, 256, 0, stream>>>(H, Hh, Hl, (int)(nX / 4));
    prep_split<<<64, 256, 0, stream>>>(W_lin, Wlh, Wll, D_ * D_ / 4);
    prep_split<<<64, 256, 0, stream>>>(W_val, Wvh, Wvl, D_ * D_ / 4);

    gemm_bf16s<true,  0><<<1024, 256, 0, stream>>>(Hh, Hl, Wlh, Wll, Xq);
    gemm_bf16s<false, 2><<<1024, 256, 0, stream>>>(Hh, Hl, Wvh, Wvl, Xvt);

    fused_edge_agg<<<4096, 256, 0, stream>>>(Xq, Xvt, src, dst, a, logA0, Yh);

    prep_split<<<64, 256, 0, stream>>>(W_out, Wouth, Woutl, D_ * D_ / 4);
    gemm_bf16s<false, 0><<<1024, 256, 0, stream>>>(Yh, Yh, Wouth, Wouth, (float*)d_out);
}

// Round 10
// 158.285 us; speedup vs baseline: 1.5566x; 1.2851x over previous
//
#include <hip/hip_runtime.h>
#include <math.h>

#define D_    256
#define NE    512
#define NNODE 64
#define NHEAD 4
#define SLOPE 0.2f
#define BTN   65536

typedef __attribute__((ext_vector_type(4))) float f32x4;
typedef __attribute__((ext_vector_type(8))) _Float16 f16x8;
typedef unsigned short u16;

__device__ inline u16 f2h(float x) {
    union { _Float16 h; u16 u; } v; v.h = (_Float16)x; return v.u;
}
__device__ inline float h2f(u16 b) {
    union { u16 u; _Float16 h; } v; v.u = b; return (float)v.h;
}

#define GLD16(g, l) __builtin_amdgcn_global_load_lds( \
    (const __attribute__((address_space(1))) void*)(g), \
    (__attribute__((address_space(3))) void*)(l), 16, 0, 0)

// ---------------------------------------------------------------------------
// Edge table: pack (src<<8)|dst and log(A0+eps) into one int2. One block.
// ---------------------------------------------------------------------------
__global__ __launch_bounds__(512) void build_edge(const int* __restrict__ src,
    const int* __restrict__ dst, const float* __restrict__ A0,
    int2* __restrict__ gedge)
{
    const int t = threadIdx.x;
    int s = src[t], d = dst[t];
    float lg = logf(A0[s * NNODE + d] + 1e-8f);
    gedge[t] = make_int2((s << 8) | d, __float_as_int(lg));
}

// ---------------------------------------------------------------------------
// fp32 -> fp16, grid-stride over float4s.
// ---------------------------------------------------------------------------
__global__ __launch_bounds__(256) void prep_hi(const float* __restrict__ s,
    u16* __restrict__ h, int n4)
{
    for (int i = blockIdx.x * 256 + threadIdx.x; i < n4; i += gridDim.x * 256) {
        float4 v = ((const float4*)s)[i];
        ((ushort4*)h)[i] = make_ushort4(f2h(v.x), f2h(v.y), f2h(v.z), f2h(v.w));
    }
}

// Three 256x256 weights -> fp16 in one launch (192 blocks).
__global__ __launch_bounds__(256) void prep_w3(const float* __restrict__ w0,
    const float* __restrict__ w1, const float* __restrict__ w2,
    u16* __restrict__ h0, u16* __restrict__ h1, u16* __restrict__ h2)
{
    int sel = blockIdx.x >> 6, b = blockIdx.x & 63;
    const float* s = sel == 0 ? w0 : sel == 1 ? w1 : w2;
    u16* h = sel == 0 ? h0 : sel == 1 ? h1 : h2;
    int i = b * 256 + threadIdx.x;
    float4 v = ((const float4*)s)[i];
    ((ushort4*)h)[i] = make_ushort4(f2h(v.x), f2h(v.y), f2h(v.z), f2h(v.w));
}

// ---------------------------------------------------------------------------
// 1-pass fp16 MFMA GEMM: C[m][n] = sum_k A[m][k]*B[n][k]. 128x128, BK=32.
// OMODE 0: fp32 row-major.
// OMODE 2: fp16 V^T slices [bt][h][dim][node], chunk ^= (dim&7) (LDS bounce).
// OMODE 3: fp16 Q slices  [bt][h][node][dim], linear (LDS bounce).
// NOTE: sT is a SEPARATE 32KB array (round-9 bug: carving it out of a 32KB
// combined buffer overflowed by 16KB for waves 2/3).
// ---------------------------------------------------------------------------
template<int OMODE>
__global__ __launch_bounds__(256) void gemm_1p(const u16* __restrict__ A,
    const u16* __restrict__ B, void* __restrict__ Cout)
{
    __shared__ u16 sA[4096], sB[4096];                   // [128][32] each, linear
    __shared__ u16 sT[OMODE >= 2 ? 16384 : 16];          // 4 waves x 8KB bounce
    const int t = threadIdx.x, lane = t & 63, wave = t >> 6;
    const int wm = wave >> 1, wn = wave & 1;
    const int bid = blockIdx.x;
    const int swz = (bid & 7) * 128 + (bid >> 3);        // XCD-contiguous
    const int m0 = (swz >> 1) * 128, n0 = (swz & 1) * 128;
    const int fr = lane & 15, kq = (lane >> 4) * 8;

    f32x4 acc[4][4];
    #pragma unroll
    for (int i = 0; i < 4; ++i)
        #pragma unroll
        for (int j = 0; j < 4; ++j) acc[i][j] = 0.f;

    for (int k0 = 0; k0 < D_; k0 += 32) {
        #pragma unroll
        for (int s = 0; s < 2; ++s) {
            const int cb = (s * 4 + wave) * 64;
            const int c  = cb + lane;
            const int row = c >> 2, ks = (c & 3) * 8;
            GLD16(A + (size_t)(m0 + row) * D_ + k0 + ks, sA + cb * 8);
            GLD16(B + (size_t)(n0 + row) * D_ + k0 + ks, sB + cb * 8);
        }
        __syncthreads();

        f16x8 fa[4];
        #pragma unroll
        for (int mi = 0; mi < 4; ++mi)
            fa[mi] = *(const f16x8*)(sA + (wm * 64 + mi * 16 + fr) * 32 + kq);
        #pragma unroll
        for (int ni = 0; ni < 4; ++ni) {
            f16x8 fb = *(const f16x8*)(sB + (wn * 64 + ni * 16 + fr) * 32 + kq);
            #pragma unroll
            for (int mi = 0; mi < 4; ++mi)
                acc[mi][ni] = __builtin_amdgcn_mfma_f32_16x16x32_f16(fa[mi], fb, acc[mi][ni], 0, 0, 0);
        }
        __syncthreads();
    }

    const int fq = (lane >> 4) * 4;   // C/D: col = lane&15, row = (lane>>4)*4 + reg
    if (OMODE == 0) {
        #pragma unroll
        for (int mi = 0; mi < 4; ++mi)
            #pragma unroll
            for (int ni = 0; ni < 4; ++ni)
                #pragma unroll
                for (int r = 0; r < 4; ++r) {
                    int m = m0 + wm * 64 + mi * 16 + fq + r;
                    int n = n0 + wn * 64 + ni * 16 + fr;
                    ((float*)Cout)[(size_t)m * D_ + n] = acc[mi][ni][r];
                }
    } else {
        // wave quadrant = one (bt,h) 64x64 slice (m -> 64 nodes, n -> 64 dims)
        u16* wT = sT + wave * 4096;
        #pragma unroll
        for (int mi = 0; mi < 4; ++mi)
            #pragma unroll
            for (int ni = 0; ni < 4; ++ni) {
                int node0 = mi * 16 + fq;          // r = 0..3 consecutive nodes
                int dim   = ni * 16 + fr;
                if (OMODE == 2) {                  // [dim][node], chunk ^= dim&7
                    ushort4 v = make_ushort4(f2h(acc[mi][ni][0]), f2h(acc[mi][ni][1]),
                                             f2h(acc[mi][ni][2]), f2h(acc[mi][ni][3]));
                    *(ushort4*)&wT[dim * 64 + (((node0 >> 3) ^ (dim & 7)) << 3) + (node0 & 7)] = v;
                } else {                           // [node][dim], linear
                    #pragma unroll
                    for (int r = 0; r < 4; ++r)
                        wT[(node0 + r) * 64 + dim] = f2h(acc[mi][ni][r]);
                }
            }
        __syncthreads();
        const int btq = (m0 >> 6) + wm;
        const int hq  = (n0 >> 6) + wn;
        u16* gx = (u16*)Cout + ((size_t)btq * NHEAD + hq) * 4096;
        #pragma unroll
        for (int r = 0; r < 8; ++r)
            *(f16x8*)&gx[r * 512 + lane * 8] = *(const f16x8*)&wT[r * 512 + lane * 8];
    }
}

// ---------------------------------------------------------------------------
// Fused edge scores + softmax + aggregation, one block per (bt, head).
// LDS exactly 32KB -> 5 blocks/CU. 3 barriers.
//   stage(Q fp16, Vt fp16, zero P) -> edge pass(score, exp, atomicAdd P) ->
//   convert(row-sum = denom, normalize, fp16 into dead Q, swizzled) ->
//   MFMA Y^T = Vt · P^T -> store Yh (fp16).
// No max-subtraction: logits ~N(0,8^2), fp32 exp safe to +-88.
// ---------------------------------------------------------------------------
__global__ __launch_bounds__(256) void fused_edge_agg(
    const u16* __restrict__ Xqh, const u16* __restrict__ Xvt,
    const int2* __restrict__ gedge, const float* __restrict__ a,
    u16* __restrict__ Yh)
{
    __shared__ u16   sQ[4096];    // 8 KB  Q [node][dim] fp16; later P fp16 (swz)
    __shared__ float sP[4096];    // 16 KB P f32 [src][dst]
    __shared__ u16   sVt[4096];   // 8 KB  V^T [dim][node], chunk ^= (dim&7)

    const int t = threadIdx.x, lane = t & 63, wave = t >> 6;
    const int grp = t >> 4, lg = t & 15;
    const int bt = blockIdx.x >> 2, h = blockIdx.x & 3;

    // ---- stage ----
    const u16* gq = Xqh + ((size_t)bt * NHEAD + h) * 4096;
    const u16* gv = Xvt + ((size_t)bt * NHEAD + h) * 4096;
    #pragma unroll
    for (int r = 0; r < 2; ++r) {
        int id = r * 256 + t;
        GLD16(gq + id * 8, (char*)sQ + id * 16);
        GLD16(gv + id * 8, (char*)sVt + id * 16);
    }
    #pragma unroll
    for (int i = 0; i < 4; ++i)
        ((float4*)sP)[t + i * 256] = make_float4(0.f, 0.f, 0.f, 0.f);
    const float4 areg = *(const float4*)&a[h * 64 + lg * 4];
    __syncthreads();

    // ---- edge pass: score -> exp -> scatter (16-lane group per edge) ----
    for (int it = 0; it < 32; ++it) {
        int e = it * 16 + grp;
        int2 ge = gedge[e];
        int s_ = ge.x >> 8, d_ = ge.x & 255;
        ushort4 qv = *(const ushort4*)&sQ[s_ * 64 + lg * 4];
        ushort4 kv = *(const ushort4*)&sQ[d_ * 64 + lg * 4];
        float x0 = h2f(qv.x) + h2f(kv.x);
        float x1 = h2f(qv.y) + h2f(kv.y);
        float x2 = h2f(qv.z) + h2f(kv.z);
        float x3 = h2f(qv.w) + h2f(kv.w);
        x0 = x0 > 0.f ? x0 : SLOPE * x0;
        x1 = x1 > 0.f ? x1 : SLOPE * x1;
        x2 = x2 > 0.f ? x2 : SLOPE * x2;
        x3 = x3 > 0.f ? x3 : SLOPE * x3;
        float p = x0 * areg.x + x1 * areg.y + x2 * areg.z + x3 * areg.w;
        p += __shfl_xor(p, 1);
        p += __shfl_xor(p, 2);
        p += __shfl_xor(p, 4);
        p += __shfl_xor(p, 8);
        if (lg == 0)
            atomicAdd(&sP[s_ * 64 + d_], __expf(p + __int_as_float(ge.y)));
    }
    __syncthreads();

    // ---- convert: row-sum -> denom; normalize; fp16 into dead Q (swizzled) ----
    {
        int s_ = t >> 2, qq = t & 3;
        const float4* row = (const float4*)&sP[s_ * 64 + qq * 16];
        float4 v0 = row[0], v1 = row[1], v2 = row[2], v3 = row[3];
        float part = v0.x + v0.y + v0.z + v0.w + v1.x + v1.y + v1.z + v1.w
                   + v2.x + v2.y + v2.z + v2.w + v3.x + v3.y + v3.z + v3.w;
        part += __shfl_xor(part, 1);
        part += __shfl_xor(part, 2);
        float inv = part > 0.f ? 1.f / part : 0.f;
        ushort4 o0 = make_ushort4(f2h(v0.x * inv), f2h(v0.y * inv),
                                  f2h(v0.z * inv), f2h(v0.w * inv));
        ushort4 o1 = make_ushort4(f2h(v1.x * inv), f2h(v1.y * inv),
                                  f2h(v1.z * inv), f2h(v1.w * inv));
        ushort4 o2 = make_ushort4(f2h(v2.x * inv), f2h(v2.y * inv),
                                  f2h(v2.z * inv), f2h(v2.w * inv));
        ushort4 o3 = make_ushort4(f2h(v3.x * inv), f2h(v3.y * inv),
                                  f2h(v3.z * inv), f2h(v3.w * inv));
        int c0 = qq * 2, c1 = qq * 2 + 1;
        u16* d0 = &sQ[s_ * 64 + ((c0 ^ (s_ & 7)) << 3)];
        u16* d1 = &sQ[s_ * 64 + ((c1 ^ (s_ & 7)) << 3)];
        *(ushort4*)d0 = o0; *(ushort4*)(d0 + 4) = o1;
        *(ushort4*)d1 = o2; *(ushort4*)(d1 + 4) = o3;
    }
    __syncthreads();

    // ---- Y^T = V^T · P^T : wave owns 16 src nodes; 8 MFMAs ----
    f32x4 acc[4];
    #pragma unroll
    for (int i = 0; i < 4; ++i) acc[i] = 0.f;
    const int fr = lane & 15, qtr = lane >> 4;
    const int srow = wave * 16 + fr;
    #pragma unroll
    for (int kk = 0; kk < 2; ++kk) {
        int g = kk * 4 + qtr;
        f16x8 fb = *(const f16x8*)&sQ[srow * 64 + ((g ^ (srow & 7)) << 3)];
        #pragma unroll
        for (int mi = 0; mi < 4; ++mi) {
            int arow = mi * 16 + fr;
            f16x8 fa = *(const f16x8*)&sVt[arow * 64 + ((g ^ (arow & 7)) << 3)];
            acc[mi] = __builtin_amdgcn_mfma_f32_16x16x32_f16(fa, fb, acc[mi], 0, 0, 0);
        }
    }

    // ---- store: col = src node, row = dim ----
    const int node = wave * 16 + fr;
    const int fq = qtr * 4;
    u16* yh = Yh + ((size_t)bt * NNODE + node) * D_ + h * 64;
    #pragma unroll
    for (int mi = 0; mi < 4; ++mi) {
        ushort4 v = make_ushort4(f2h(acc[mi][0]), f2h(acc[mi][1]),
                                 f2h(acc[mi][2]), f2h(acc[mi][3]));
        *(ushort4*)&yh[mi * 16 + fq] = v;
    }
}

// ---------------------------------------------------------------------------
extern "C" void kernel_launch(void* const* d_in, const int* in_sizes, int n_in,
                              void* d_out, int out_size, void* d_ws, size_t ws_size,
                              hipStream_t stream)
{
    const float* H     = (const float*)d_in[0];
    const float* W_lin = (const float*)d_in[1];
    const float* W_val = (const float*)d_in[2];
    const float* a     = (const float*)d_in[3];
    const float* W_out = (const float*)d_in[4];
    const float* A0    = (const float*)d_in[5];
    const int*   src   = (const int*)d_in[6];
    const int*   dst   = (const int*)d_in[7];

    const size_t nX = (size_t)BTN * D_;              // 16777216 elems
    // ws layout: Hh [0,32M) | Xqh [32M,64M) | W's + gedge [64M, ~64.5M)
    u16* Hh  = (u16*)d_ws;
    u16* Xqh = Hh + nX;
    u16* Wlh   = Xqh + nX;
    u16* Wvh   = Wlh + D_ * D_;
    u16* Wouth = Wvh + D_ * D_;
    int2* gedge = (int2*)(Wouth + D_ * D_);
    u16* Yh = Hh;                                    // alias: Hh dead after GEMM2
    if (ws_size < (size_t)134217728) return;

    u16* Xvt = (u16*)d_out;                          // d_out scratch until GEMM3

    build_edge<<<1, 512, 0, stream>>>(src, dst, A0, gedge);
    prep_hi<<<4096, 256, 0, stream>>>(H, Hh, (int)(nX / 4));
    prep_w3<<<192, 256, 0, stream>>>(W_lin, W_val, W_out, Wlh, Wvh, Wouth);

    gemm_1p<3><<<1024, 256, 0, stream>>>(Hh, Wlh, Xqh);   // Q fp16 slices
    gemm_1p<2><<<1024, 256, 0, stream>>>(Hh, Wvh, Xvt);   // V^T fp16 slices

    fused_edge_agg<<<4096, 256, 0, stream>>>(Xqh, Xvt, gedge, a, Yh);

    gemm_1p<0><<<1024, 256, 0, stream>>>(Yh, Wouth, (float*)d_out);
}

// Round 12
// 151.123 us; speedup vs baseline: 1.6304x; 1.0474x over previous
//
#include <hip/hip_runtime.h>
#include <math.h>

#define D_    256
#define NE    512
#define NNODE 64
#define NHEAD 4
#define SLOPE 0.2f
#define BTN   65536

typedef __attribute__((ext_vector_type(4))) float f32x4;
typedef __attribute__((ext_vector_type(8))) _Float16 f16x8;
typedef __attribute__((ext_vector_type(4))) _Float16 f16x4;
typedef __attribute__((ext_vector_type(2))) _Float16 f16x2;
typedef __attribute__((ext_vector_type(2))) __fp16   h16x2;   // builtin interop
typedef unsigned short u16;

__device__ inline u16 f2h(float x) {
    union { _Float16 h; u16 u; } v; v.h = (_Float16)x; return v.u;
}
__device__ inline float h2f(u16 b) {
    union { u16 u; _Float16 h; } v; v.u = b; return (float)v.h;
}
__device__ inline f16x2 pkrtz(float lo, float hi) {
    h16x2 r = __builtin_amdgcn_cvt_pkrtz(lo, hi);
    f16x2 o; __builtin_memcpy(&o, &r, 4); return o;
}
__device__ inline float dot2(f16x2 x, f16x2 a, float c) {
#if __has_builtin(__builtin_amdgcn_fdot2)
    h16x2 xx, aa;
    __builtin_memcpy(&xx, &x, 4);
    __builtin_memcpy(&aa, &a, 4);
    return __builtin_amdgcn_fdot2(xx, aa, c, false);
#else
    return c + (float)x[0] * (float)a[0] + (float)x[1] * (float)a[1];
#endif
}

#define GLD16(g, l) __builtin_amdgcn_global_load_lds( \
    (const __attribute__((address_space(1))) void*)(g), \
    (__attribute__((address_space(3))) void*)(l), 16, 0, 0)

// ---------------------------------------------------------------------------
// Edge table: pack (src<<8)|dst and log(A0+eps) into one int2. One block.
// ---------------------------------------------------------------------------
__global__ __launch_bounds__(512) void build_edge(const int* __restrict__ src,
    const int* __restrict__ dst, const float* __restrict__ A0,
    int2* __restrict__ gedge)
{
    const int t = threadIdx.x;
    int s = src[t], d = dst[t];
    float lg = logf(A0[s * NNODE + d] + 1e-8f);
    gedge[t] = make_int2((s << 8) | d, __float_as_int(lg));
}

// ---------------------------------------------------------------------------
// fp32 -> fp16, grid-stride over float4s.
// ---------------------------------------------------------------------------
__global__ __launch_bounds__(256) void prep_hi(const float* __restrict__ s,
    u16* __restrict__ h, int n4)
{
    for (int i = blockIdx.x * 256 + threadIdx.x; i < n4; i += gridDim.x * 256) {
        float4 v = ((const float4*)s)[i];
        ((ushort4*)h)[i] = make_ushort4(f2h(v.x), f2h(v.y), f2h(v.z), f2h(v.w));
    }
}

// Three 256x256 weights -> fp16 in one launch (192 blocks).
__global__ __launch_bounds__(256) void prep_w3(const float* __restrict__ w0,
    const float* __restrict__ w1, const float* __restrict__ w2,
    u16* __restrict__ h0, u16* __restrict__ h1, u16* __restrict__ h2)
{
    int sel = blockIdx.x >> 6, b = blockIdx.x & 63;
    const float* s = sel == 0 ? w0 : sel == 1 ? w1 : w2;
    u16* h = sel == 0 ? h0 : sel == 1 ? h1 : h2;
    int i = b * 256 + threadIdx.x;
    float4 v = ((const float4*)s)[i];
    ((ushort4*)h)[i] = make_ushort4(f2h(v.x), f2h(v.y), f2h(v.z), f2h(v.w));
}

// ---------------------------------------------------------------------------
// 1-pass fp16 MFMA GEMM: C[m][n] = sum_k A[m][k]*B[n][k]. 128x128, BK=32.
// OMODE 0: fp32 row-major.
// OMODE 2: fp16 V^T slices [bt][h][dim][node], chunk ^= (dim&7) (LDS bounce).
// OMODE 3: fp16 Q slices  [bt][h][node][dim], linear (LDS bounce).
// ---------------------------------------------------------------------------
template<int OMODE>
__global__ __launch_bounds__(256) void gemm_1p(const u16* __restrict__ A,
    const u16* __restrict__ B, void* __restrict__ Cout)
{
    __shared__ u16 sA[4096], sB[4096];                   // [128][32] each, linear
    __shared__ u16 sT[OMODE >= 2 ? 16384 : 16];          // 4 waves x 8KB bounce
    const int t = threadIdx.x, lane = t & 63, wave = t >> 6;
    const int wm = wave >> 1, wn = wave & 1;
    const int bid = blockIdx.x;
    const int swz = (bid & 7) * 128 + (bid >> 3);        // XCD-contiguous
    const int m0 = (swz >> 1) * 128, n0 = (swz & 1) * 128;
    const int fr = lane & 15, kq = (lane >> 4) * 8;

    f32x4 acc[4][4];
    #pragma unroll
    for (int i = 0; i < 4; ++i)
        #pragma unroll
        for (int j = 0; j < 4; ++j) acc[i][j] = 0.f;

    for (int k0 = 0; k0 < D_; k0 += 32) {
        #pragma unroll
        for (int s = 0; s < 2; ++s) {
            const int cb = (s * 4 + wave) * 64;
            const int c  = cb + lane;
            const int row = c >> 2, ks = (c & 3) * 8;
            GLD16(A + (size_t)(m0 + row) * D_ + k0 + ks, sA + cb * 8);
            GLD16(B + (size_t)(n0 + row) * D_ + k0 + ks, sB + cb * 8);
        }
        __syncthreads();

        f16x8 fa[4];
        #pragma unroll
        for (int mi = 0; mi < 4; ++mi)
            fa[mi] = *(const f16x8*)(sA + (wm * 64 + mi * 16 + fr) * 32 + kq);
        #pragma unroll
        for (int ni = 0; ni < 4; ++ni) {
            f16x8 fb = *(const f16x8*)(sB + (wn * 64 + ni * 16 + fr) * 32 + kq);
            #pragma unroll
            for (int mi = 0; mi < 4; ++mi)
                acc[mi][ni] = __builtin_amdgcn_mfma_f32_16x16x32_f16(fa[mi], fb, acc[mi][ni], 0, 0, 0);
        }
        __syncthreads();
    }

    const int fq = (lane >> 4) * 4;   // C/D: col = lane&15, row = (lane>>4)*4 + reg
    if (OMODE == 0) {
        #pragma unroll
        for (int mi = 0; mi < 4; ++mi)
            #pragma unroll
            for (int ni = 0; ni < 4; ++ni)
                #pragma unroll
                for (int r = 0; r < 4; ++r) {
                    int m = m0 + wm * 64 + mi * 16 + fq + r;
                    int n = n0 + wn * 64 + ni * 16 + fr;
                    ((float*)Cout)[(size_t)m * D_ + n] = acc[mi][ni][r];
                }
    } else {
        // wave quadrant = one (bt,h) 64x64 slice (m -> 64 nodes, n -> 64 dims)
        u16* wT = sT + wave * 4096;
        #pragma unroll
        for (int mi = 0; mi < 4; ++mi)
            #pragma unroll
            for (int ni = 0; ni < 4; ++ni) {
                int node0 = mi * 16 + fq;          // r = 0..3 consecutive nodes
                int dim   = ni * 16 + fr;
                if (OMODE == 2) {                  // [dim][node], chunk ^= dim&7
                    ushort4 v = make_ushort4(f2h(acc[mi][ni][0]), f2h(acc[mi][ni][1]),
                                             f2h(acc[mi][ni][2]), f2h(acc[mi][ni][3]));
                    *(ushort4*)&wT[dim * 64 + (((node0 >> 3) ^ (dim & 7)) << 3) + (node0 & 7)] = v;
                } else {                           // [node][dim], linear
                    #pragma unroll
                    for (int r = 0; r < 4; ++r)
                        wT[(node0 + r) * 64 + dim] = f2h(acc[mi][ni][r]);
                }
            }
        __syncthreads();
        const int btq = (m0 >> 6) + wm;
        const int hq  = (n0 >> 6) + wn;
        u16* gx = (u16*)Cout + ((size_t)btq * NHEAD + hq) * 4096;
        #pragma unroll
        for (int r = 0; r < 8; ++r)
            *(f16x8*)&gx[r * 512 + lane * 8] = *(const f16x8*)&wT[r * 512 + lane * 8];
    }
}

// ---------------------------------------------------------------------------
// Fused edge scores + softmax + aggregation, one block per (bt, head).
// LDS 24.4KB (Q 8K + P 16K + a/b tables). V^T fragments live in REGISTERS
// (loaded from global at start; slice read exactly once -> no LDS staging).
// Edge score via lrelu(x)=0.6x+0.4|x|:
//   e = 0.6*(b[s]+b[d]) + 0.4*sum|q_s+q_d|*a + logA0,  b[n] = <q_n, a>.
// Per-edge work is packed fp16: v_pk_add_f16 + and(0x7FFF7FFF) + v_dot2_f32_f16.
// ---------------------------------------------------------------------------
__global__ __launch_bounds__(256, 5) void fused_edge_agg(
    const u16* __restrict__ Xqh, const u16* __restrict__ Xvt,
    const int2* __restrict__ gedge, const float* __restrict__ a,
    u16* __restrict__ Yh)
{
    __shared__ u16   sQ[4096];    // 8 KB  Q [node][dim] fp16; later P fp16 (swz)
    __shared__ float sP[4096];    // 16 KB P f32 [src][dst]
    __shared__ u16   sAh[64];     // a (this head) fp16
    __shared__ float sBn[NNODE];  // b[n] = <q_n, a>

    const int t = threadIdx.x, lane = t & 63, wave = t >> 6;
    const int grp = t >> 4, lg = t & 15;
    const int fr = lane & 15, qtr = lane >> 4;
    const int bt = blockIdx.x >> 2, h = blockIdx.x & 3;

    // ---- V^T fragments: direct global -> register (slice read exactly once).
    // Layout has chunk ^= (dim&7) baked in by GEMM2's epilogue.
    const u16* gv = Xvt + ((size_t)bt * NHEAD + h) * 4096;
    f16x8 vf[2][4];
    #pragma unroll
    for (int kk = 0; kk < 2; ++kk) {
        int g = kk * 4 + qtr;
        #pragma unroll
        for (int mi = 0; mi < 4; ++mi) {
            int arow = mi * 16 + fr;
            vf[kk][mi] = *(const f16x8*)&gv[arow * 64 + ((g ^ (arow & 7)) << 3)];
        }
    }

    // ---- stage Q + a; zero P ----
    const u16* gq = Xqh + ((size_t)bt * NHEAD + h) * 4096;
    #pragma unroll
    for (int r = 0; r < 2; ++r) {
        int id = r * 256 + t;
        GLD16(gq + id * 8, (char*)sQ + id * 16);
    }
    if (t < 16) {
        float4 av = *(const float4*)&a[h * 64 + t * 4];
        *(f16x2*)&sAh[t * 4]     = pkrtz(av.x, av.y);
        *(f16x2*)&sAh[t * 4 + 2] = pkrtz(av.z, av.w);
    }
    #pragma unroll
    for (int i = 0; i < 4; ++i)
        ((float4*)sP)[t + i * 256] = make_float4(0.f, 0.f, 0.f, 0.f);
    __syncthreads();

    // ---- b[n] = <q_n, a>: 4 threads per node, 16 dims each ----
    {
        int n = t >> 2, qq = t & 3;
        const f16x2* qrow = (const f16x2*)&sQ[n * 64 + qq * 16];
        const f16x2* arow = (const f16x2*)&sAh[qq * 16];
        float b = 0.f;
        #pragma unroll
        for (int c = 0; c < 8; ++c) b = dot2(qrow[c], arow[c], b);
        b += __shfl_xor(b, 1);
        b += __shfl_xor(b, 2);
        if (qq == 0) sBn[n] = b;
    }
    const f16x2 a01 = *(const f16x2*)&sAh[lg * 4];
    const f16x2 a23 = *(const f16x2*)&sAh[lg * 4 + 2];
    __syncthreads();

    // ---- edge pass: 16-lane group per edge; packed fp16 abs-dot ----
    for (int it = 0; it < 32; ++it) {
        int e = it * 16 + grp;
        int2 ge = gedge[e];
        int s_ = ge.x >> 8, d_ = ge.x & 255;
        f16x4 qv = *(const f16x4*)&sQ[s_ * 64 + lg * 4];
        f16x4 kv = *(const f16x4*)&sQ[d_ * 64 + lg * 4];
        f16x4 x = qv + kv;                        // 2x v_pk_add_f16
        unsigned xu[2];
        __builtin_memcpy(xu, &x, 8);
        xu[0] &= 0x7FFF7FFFu; xu[1] &= 0x7FFF7FFFu;
        f16x2 xa0, xa1;
        __builtin_memcpy(&xa0, &xu[0], 4);
        __builtin_memcpy(&xa1, &xu[1], 4);
        float p = dot2(xa0, a01, 0.f);
        p = dot2(xa1, a23, p);
        p += __shfl_xor(p, 1);
        p += __shfl_xor(p, 2);
        p += __shfl_xor(p, 4);
        p += __shfl_xor(p, 8);
        if (lg == 0) {
            float sc = 0.6f * (sBn[s_] + sBn[d_]) + 0.4f * p + __int_as_float(ge.y);
            atomicAdd(&sP[s_ * 64 + d_], __expf(sc));
        }
    }
    __syncthreads();

    // ---- convert: row-sum -> denom; normalize; fp16 into dead Q (swizzled) ----
    {
        int s_ = t >> 2, qq = t & 3;
        const float4* row = (const float4*)&sP[s_ * 64 + qq * 16];
        float4 v0 = row[0], v1 = row[1], v2 = row[2], v3 = row[3];
        float part = v0.x + v0.y + v0.z + v0.w + v1.x + v1.y + v1.z + v1.w
                   + v2.x + v2.y + v2.z + v2.w + v3.x + v3.y + v3.z + v3.w;
        part += __shfl_xor(part, 1);
        part += __shfl_xor(part, 2);
        float inv = part > 0.f ? 1.f / part : 0.f;
        f16x2 p0 = pkrtz(v0.x * inv, v0.y * inv), p1 = pkrtz(v0.z * inv, v0.w * inv);
        f16x2 p2 = pkrtz(v1.x * inv, v1.y * inv), p3 = pkrtz(v1.z * inv, v1.w * inv);
        f16x2 p4 = pkrtz(v2.x * inv, v2.y * inv), p5 = pkrtz(v2.z * inv, v2.w * inv);
        f16x2 p6 = pkrtz(v3.x * inv, v3.y * inv), p7 = pkrtz(v3.z * inv, v3.w * inv);
        int c0 = qq * 2, c1 = qq * 2 + 1;
        u16* d0 = &sQ[s_ * 64 + ((c0 ^ (s_ & 7)) << 3)];
        u16* d1 = &sQ[s_ * 64 + ((c1 ^ (s_ & 7)) << 3)];
        ((f16x2*)d0)[0] = p0; ((f16x2*)d0)[1] = p1;
        ((f16x2*)d0)[2] = p2; ((f16x2*)d0)[3] = p3;
        ((f16x2*)d1)[0] = p4; ((f16x2*)d1)[1] = p5;
        ((f16x2*)d1)[2] = p6; ((f16x2*)d1)[3] = p7;
    }
    __syncthreads();

    // ---- Y^T = V^T · P^T : wave owns 16 src nodes; 8 MFMAs (A from regs) ----
    f32x4 acc[4];
    #pragma unroll
    for (int i = 0; i < 4; ++i) acc[i] = 0.f;
    const int srow = wave * 16 + fr;
    #pragma unroll
    for (int kk = 0; kk < 2; ++kk) {
        int g = kk * 4 + qtr;
        f16x8 fb = *(const f16x8*)&sQ[srow * 64 + ((g ^ (srow & 7)) << 3)];
        #pragma unroll
        for (int mi = 0; mi < 4; ++mi)
            acc[mi] = __builtin_amdgcn_mfma_f32_16x16x32_f16(vf[kk][mi], fb, acc[mi], 0, 0, 0);
    }

    // ---- store: col = src node, row = dim ----
    const int node = wave * 16 + fr;
    const int fq = qtr * 4;
    u16* yh = Yh + ((size_t)bt * NNODE + node) * D_ + h * 64;
    #pragma unroll
    for (int mi = 0; mi < 4; ++mi) {
        ushort4 v = make_ushort4(f2h(acc[mi][0]), f2h(acc[mi][1]),
                                 f2h(acc[mi][2]), f2h(acc[mi][3]));
        *(ushort4*)&yh[mi * 16 + fq] = v;
    }
}

// ---------------------------------------------------------------------------
extern "C" void kernel_launch(void* const* d_in, const int* in_sizes, int n_in,
                              void* d_out, int out_size, void* d_ws, size_t ws_size,
                              hipStream_t stream)
{
    const float* H     = (const float*)d_in[0];
    const float* W_lin = (const float*)d_in[1];
    const float* W_val = (const float*)d_in[2];
    const float* a     = (const float*)d_in[3];
    const float* W_out = (const float*)d_in[4];
    const float* A0    = (const float*)d_in[5];
    const int*   src   = (const int*)d_in[6];
    const int*   dst   = (const int*)d_in[7];

    const size_t nX = (size_t)BTN * D_;              // 16777216 elems
    // ws layout: Hh [0,32M) | Xqh [32M,64M) | W's + gedge [64M, ~64.5M)
    u16* Hh  = (u16*)d_ws;
    u16* Xqh = Hh + nX;
    u16* Wlh   = Xqh + nX;
    u16* Wvh   = Wlh + D_ * D_;
    u16* Wouth = Wvh + D_ * D_;
    int2* gedge = (int2*)(Wouth + D_ * D_);
    u16* Yh = Hh;                                    // alias: Hh dead after GEMM2
    if (ws_size < (size_t)134217728) return;

    u16* Xvt = (u16*)d_out;                          // d_out scratch until GEMM3

    build_edge<<<1, 512, 0, stream>>>(src, dst, A0, gedge);
    prep_hi<<<4096, 256, 0, stream>>>(H, Hh, (int)(nX / 4));
    prep_w3<<<192, 256, 0, stream>>>(W_lin, W_val, W_out, Wlh, Wvh, Wouth);

    gemm_1p<3><<<1024, 256, 0, stream>>>(Hh, Wlh, Xqh);   // Q fp16 slices
    gemm_1p<2><<<1024, 256, 0, stream>>>(Hh, Wvh, Xvt);   // V^T fp16 slices

    fused_edge_agg<<<4096, 256, 0, stream>>>(Xqh, Xvt, gedge, a, Yh);

    gemm_1p<0><<<1024, 256, 0, stream>>>(Yh, Wouth, (float*)d_out);
}

// Round 13
// 120.322 us; speedup vs baseline: 2.0478x; 1.2560x over previous
//
#include <hip/hip_runtime.h>
#include <math.h>

#define D_    256
#define NE    512
#define NNODE 64
#define NHEAD 4
#define SLOPE 0.2f
#define BTN   65536

typedef __attribute__((ext_vector_type(4))) float f32x4;
typedef __attribute__((ext_vector_type(8))) _Float16 f16x8;
typedef __attribute__((ext_vector_type(2))) _Float16 f16x2;
typedef __attribute__((ext_vector_type(2))) __fp16   h16x2;   // builtin interop
typedef unsigned short u16;

__device__ inline u16 f2h(float x) {
    union { _Float16 h; u16 u; } v; v.h = (_Float16)x; return v.u;
}
__device__ inline float h2f(u16 b) {
    union { u16 u; _Float16 h; } v; v.u = b; return (float)v.h;
}
__device__ inline f16x2 pkrtz(float lo, float hi) {
    h16x2 r = __builtin_amdgcn_cvt_pkrtz(lo, hi);
    f16x2 o; __builtin_memcpy(&o, &r, 4); return o;
}

#define GLD16(g, l) __builtin_amdgcn_global_load_lds( \
    (const __attribute__((address_space(1))) void*)(g), \
    (__attribute__((address_space(3))) void*)(l), 16, 0, 0)

// ---------------------------------------------------------------------------
// Edge table: pack (src<<8)|dst and log(A0+eps) into one int2. One block.
// ---------------------------------------------------------------------------
__global__ __launch_bounds__(512) void build_edge(const int* __restrict__ src,
    const int* __restrict__ dst, const float* __restrict__ A0,
    int2* __restrict__ gedge)
{
    const int t = threadIdx.x;
    int s = src[t], d = dst[t];
    float lg = logf(A0[s * NNODE + d] + 1e-8f);
    gedge[t] = make_int2((s << 8) | d, __float_as_int(lg));
}

// ---------------------------------------------------------------------------
// fp32 -> fp16, grid-stride over float4s.
// ---------------------------------------------------------------------------
__global__ __launch_bounds__(256) void prep_hi(const float* __restrict__ s,
    u16* __restrict__ h, int n4)
{
    for (int i = blockIdx.x * 256 + threadIdx.x; i < n4; i += gridDim.x * 256) {
        float4 v = ((const float4*)s)[i];
        ((ushort4*)h)[i] = make_ushort4(f2h(v.x), f2h(v.y), f2h(v.z), f2h(v.w));
    }
}

// Three 256x256 weights -> fp16 in one launch (192 blocks).
__global__ __launch_bounds__(256) void prep_w3(const float* __restrict__ w0,
    const float* __restrict__ w1, const float* __restrict__ w2,
    u16* __restrict__ h0, u16* __restrict__ h1, u16* __restrict__ h2)
{
    int sel = blockIdx.x >> 6, b = blockIdx.x & 63;
    const float* s = sel == 0 ? w0 : sel == 1 ? w1 : w2;
    u16* h = sel == 0 ? h0 : sel == 1 ? h1 : h2;
    int i = b * 256 + threadIdx.x;
    float4 v = ((const float4*)s)[i];
    ((ushort4*)h)[i] = make_ushort4(f2h(v.x), f2h(v.y), f2h(v.z), f2h(v.w));
}

// ---------------------------------------------------------------------------
// 1-pass fp16 MFMA GEMM: C[m][n] = sum_k A[m][k]*B[n][k]. 128x128, BK=32.
// OMODE 0: fp32 row-major.
// OMODE 2: fp16 V^T slices [bt][h][dim][node], chunk ^= (dim&7) (LDS bounce).
// OMODE 3: fp16 Q slices  [bt][h][node][dim], chunk ^= (node&7) (LDS bounce).
// ---------------------------------------------------------------------------
template<int OMODE>
__global__ __launch_bounds__(256) void gemm_1p(const u16* __restrict__ A,
    const u16* __restrict__ B, void* __restrict__ Cout)
{
    __shared__ u16 sA[4096], sB[4096];                   // [128][32] each, linear
    __shared__ u16 sT[OMODE >= 2 ? 16384 : 16];          // 4 waves x 8KB bounce
    const int t = threadIdx.x, lane = t & 63, wave = t >> 6;
    const int wm = wave >> 1, wn = wave & 1;
    const int bid = blockIdx.x;
    const int swz = (bid & 7) * 128 + (bid >> 3);        // XCD-contiguous
    const int m0 = (swz >> 1) * 128, n0 = (swz & 1) * 128;
    const int fr = lane & 15, kq = (lane >> 4) * 8;

    f32x4 acc[4][4];
    #pragma unroll
    for (int i = 0; i < 4; ++i)
        #pragma unroll
        for (int j = 0; j < 4; ++j) acc[i][j] = 0.f;

    for (int k0 = 0; k0 < D_; k0 += 32) {
        #pragma unroll
        for (int s = 0; s < 2; ++s) {
            const int cb = (s * 4 + wave) * 64;
            const int c  = cb + lane;
            const int row = c >> 2, ks = (c & 3) * 8;
            GLD16(A + (size_t)(m0 + row) * D_ + k0 + ks, sA + cb * 8);
            GLD16(B + (size_t)(n0 + row) * D_ + k0 + ks, sB + cb * 8);
        }
        __syncthreads();

        f16x8 fa[4];
        #pragma unroll
        for (int mi = 0; mi < 4; ++mi)
            fa[mi] = *(const f16x8*)(sA + (wm * 64 + mi * 16 + fr) * 32 + kq);
        #pragma unroll
        for (int ni = 0; ni < 4; ++ni) {
            f16x8 fb = *(const f16x8*)(sB + (wn * 64 + ni * 16 + fr) * 32 + kq);
            #pragma unroll
            for (int mi = 0; mi < 4; ++mi)
                acc[mi][ni] = __builtin_amdgcn_mfma_f32_16x16x32_f16(fa[mi], fb, acc[mi][ni], 0, 0, 0);
        }
        __syncthreads();
    }

    const int fq = (lane >> 4) * 4;   // C/D: col = lane&15, row = (lane>>4)*4 + reg
    if (OMODE == 0) {
        #pragma unroll
        for (int mi = 0; mi < 4; ++mi)
            #pragma unroll
            for (int ni = 0; ni < 4; ++ni)
                #pragma unroll
                for (int r = 0; r < 4; ++r) {
                    int m = m0 + wm * 64 + mi * 16 + fq + r;
                    int n = n0 + wn * 64 + ni * 16 + fr;
                    ((float*)Cout)[(size_t)m * D_ + n] = acc[mi][ni][r];
                }
    } else {
        // wave quadrant = one (bt,h) 64x64 slice (m -> 64 nodes, n -> 64 dims)
        u16* wT = sT + wave * 4096;
        #pragma unroll
        for (int mi = 0; mi < 4; ++mi)
            #pragma unroll
            for (int ni = 0; ni < 4; ++ni) {
                int node0 = mi * 16 + fq;          // r = 0..3 consecutive nodes
                int dim   = ni * 16 + fr;
                if (OMODE == 2) {                  // [dim][node], chunk ^= dim&7
                    ushort4 v = make_ushort4(f2h(acc[mi][ni][0]), f2h(acc[mi][ni][1]),
                                             f2h(acc[mi][ni][2]), f2h(acc[mi][ni][3]));
                    *(ushort4*)&wT[dim * 64 + (((node0 >> 3) ^ (dim & 7)) << 3) + (node0 & 7)] = v;
                } else {                           // [node][dim], chunk ^= node&7
                    #pragma unroll
                    for (int r = 0; r < 4; ++r) {
                        int node = node0 + r;
                        wT[node * 64 + ((((dim >> 3) ^ (node & 7))) << 3) + (dim & 7)]
                            = f2h(acc[mi][ni][r]);
                    }
                }
            }
        __syncthreads();
        const int btq = (m0 >> 6) + wm;
        const int hq  = (n0 >> 6) + wn;
        u16* gx = (u16*)Cout + ((size_t)btq * NHEAD + hq) * 4096;
        #pragma unroll
        for (int r = 0; r < 8; ++r)
            *(f16x8*)&gx[r * 512 + lane * 8] = *(const f16x8*)&wT[r * 512 + lane * 8];
    }
}

// ---------------------------------------------------------------------------
// Fused edge scores + softmax + aggregation, one block per (bt, head).
// Edge scores via MFMA: per 16-edge tile, A = |q_s+q_d| (rows=edges),
// B = 0.4*a replicated -> D[m][*] = abs-dot. lrelu linear part hoisted:
// sLin[e] = 0.6*(b[s]+b[d]) + logA0. No cross-lane shuffles in the edge pass.
// Q layout (global+LDS): [node][dim] with chunk ^= (node&7)  [T2 both-sides].
// LDS ~28.9KB -> 5 blocks/CU.
// ---------------------------------------------------------------------------
__global__ __launch_bounds__(256, 5) void fused_edge_agg(
    const u16* __restrict__ Xqh, const u16* __restrict__ Xvt,
    const int2* __restrict__ gedge, const float* __restrict__ a,
    u16* __restrict__ Yh)
{
    __shared__ u16   sQ[4096];    // 8 KB  Q fp16 swizzled; later P fp16 (swz)
    __shared__ float sP[4096];    // 16 KB P f32 [src][dst]
    __shared__ float sBn[NNODE];  // b[n] = <q_n, a>
    __shared__ float sLin[NE];    // 0.6*(b_s+b_d) + logA0
    __shared__ int   sPack[NE];   // (src<<8)|dst

    const int t = threadIdx.x, lane = t & 63, wave = t >> 6;
    const int fr = lane & 15, qtr = lane >> 4;
    const int bt = blockIdx.x >> 2, h = blockIdx.x & 3;

    // ---- V^T fragments: direct global -> register (chunk ^= dim&7 baked) ----
    const u16* gv = Xvt + ((size_t)bt * NHEAD + h) * 4096;
    f16x8 vf[2][4];
    #pragma unroll
    for (int kk = 0; kk < 2; ++kk) {
        int g = kk * 4 + qtr;
        #pragma unroll
        for (int mi = 0; mi < 4; ++mi) {
            int arow = mi * 16 + fr;
            vf[kk][mi] = *(const f16x8*)&gv[arow * 64 + ((g ^ (arow & 7)) << 3)];
        }
    }
    // ---- B-fragments for the score MFMA: 0.4*a, replicated rows ----
    f16x8 af[2];
    #pragma unroll
    for (int kk = 0; kk < 2; ++kk) {
        const float* ab = a + h * 64 + kk * 32 + qtr * 8;
        float4 a0 = *(const float4*)ab, a1 = *(const float4*)(ab + 4);
        af[kk][0] = (_Float16)(0.4f * a0.x); af[kk][1] = (_Float16)(0.4f * a0.y);
        af[kk][2] = (_Float16)(0.4f * a0.z); af[kk][3] = (_Float16)(0.4f * a0.w);
        af[kk][4] = (_Float16)(0.4f * a1.x); af[kk][5] = (_Float16)(0.4f * a1.y);
        af[kk][6] = (_Float16)(0.4f * a1.z); af[kk][7] = (_Float16)(0.4f * a1.w);
    }

    // ---- stage Q (already swizzled in global); zero P ----
    const u16* gq = Xqh + ((size_t)bt * NHEAD + h) * 4096;
    #pragma unroll
    for (int r = 0; r < 2; ++r) {
        int id = r * 256 + t;
        GLD16(gq + id * 8, (char*)sQ + id * 16);
    }
    #pragma unroll
    for (int i = 0; i < 4; ++i)
        ((float4*)sP)[t + i * 256] = make_float4(0.f, 0.f, 0.f, 0.f);
    __syncthreads();

    // ---- b[n] = <q_n, a>: 4 threads per node, 16 dims each (swizzled read) ----
    {
        int n = t >> 2, qq = t & 3;
        float b = 0.f;
        #pragma unroll
        for (int j = 0; j < 2; ++j) {
            int ck = qq * 2 + j;
            f16x8 qv = *(const f16x8*)&sQ[n * 64 + ((ck ^ (n & 7)) << 3)];
            const float* ab = a + h * 64 + ck * 8;
            float4 a0 = *(const float4*)ab, a1 = *(const float4*)(ab + 4);
            b = fmaf((float)qv[0], a0.x, b); b = fmaf((float)qv[1], a0.y, b);
            b = fmaf((float)qv[2], a0.z, b); b = fmaf((float)qv[3], a0.w, b);
            b = fmaf((float)qv[4], a1.x, b); b = fmaf((float)qv[5], a1.y, b);
            b = fmaf((float)qv[6], a1.z, b); b = fmaf((float)qv[7], a1.w, b);
        }
        b += __shfl_xor(b, 1);
        b += __shfl_xor(b, 2);
        if (qq == 0) sBn[n] = b;
    }
    __syncthreads();

    // ---- edge tables: sPack + hoisted linear term ----
    #pragma unroll
    for (int i = 0; i < 2; ++i) {
        int e = t + i * 256;
        int2 ge = gedge[e];
        int s_ = ge.x >> 8, d_ = ge.x & 255;
        sPack[e] = ge.x;
        sLin[e] = 0.6f * (sBn[s_] + sBn[d_]) + __int_as_float(ge.y);
    }
    __syncthreads();

    // ---- edge pass: 8 tiles/wave x 16 edges, scores via MFMA ----
    const int wbase = wave * 128;
    #pragma unroll
    for (int tt = 0; tt < 8; ++tt) {
        int e = wbase + tt * 16 + fr;
        int pk = sPack[e];
        int s_ = pk >> 8, d_ = pk & 255;
        f32x4 acc = 0.f;
        #pragma unroll
        for (int kk = 0; kk < 2; ++kk) {
            int ck = kk * 4 + qtr;
            f16x8 qs = *(const f16x8*)&sQ[s_ * 64 + ((ck ^ (s_ & 7)) << 3)];
            f16x8 qd = *(const f16x8*)&sQ[d_ * 64 + ((ck ^ (d_ & 7)) << 3)];
            f16x8 x = qs + qd;                       // 4x v_pk_add_f16
            unsigned xu[4];
            __builtin_memcpy(xu, &x, 16);
            xu[0] &= 0x7FFF7FFFu; xu[1] &= 0x7FFF7FFFu;
            xu[2] &= 0x7FFF7FFFu; xu[3] &= 0x7FFF7FFFu;
            f16x8 xa;
            __builtin_memcpy(&xa, xu, 16);
            acc = __builtin_amdgcn_mfma_f32_16x16x32_f16(xa, af[kk], acc, 0, 0, 0);
        }
        // D rows = edges; lane holds rows qtr*4+0..3 (all cols equal).
        // Writers: cols 0..3 of each quarter, one edge each (no dyn vec index).
        int c = lane & 15;
        if (c < 4) {
            float av = c == 0 ? acc[0] : c == 1 ? acc[1] : c == 2 ? acc[2] : acc[3];
            int eg = wbase + tt * 16 + qtr * 4 + c;
            int pk2 = sPack[eg];
            atomicAdd(&sP[(pk2 >> 8) * 64 + (pk2 & 255)], __expf(av + sLin[eg]));
        }
    }
    __syncthreads();

    // ---- convert: row-sum -> denom; normalize; fp16 into dead Q (swizzled) ----
    {
        int s_ = t >> 2, qq = t & 3;
        const float4* row = (const float4*)&sP[s_ * 64 + qq * 16];
        float4 v0 = row[0], v1 = row[1], v2 = row[2], v3 = row[3];
        float part = v0.x + v0.y + v0.z + v0.w + v1.x + v1.y + v1.z + v1.w
                   + v2.x + v2.y + v2.z + v2.w + v3.x + v3.y + v3.z + v3.w;
        part += __shfl_xor(part, 1);
        part += __shfl_xor(part, 2);
        float inv = part > 0.f ? 1.f / part : 0.f;
        f16x2 p0 = pkrtz(v0.x * inv, v0.y * inv), p1 = pkrtz(v0.z * inv, v0.w * inv);
        f16x2 p2 = pkrtz(v1.x * inv, v1.y * inv), p3 = pkrtz(v1.z * inv, v1.w * inv);
        f16x2 p4 = pkrtz(v2.x * inv, v2.y * inv), p5 = pkrtz(v2.z * inv, v2.w * inv);
        f16x2 p6 = pkrtz(v3.x * inv, v3.y * inv), p7 = pkrtz(v3.z * inv, v3.w * inv);
        int c0 = qq * 2, c1 = qq * 2 + 1;
        u16* d0 = &sQ[s_ * 64 + ((c0 ^ (s_ & 7)) << 3)];
        u16* d1 = &sQ[s_ * 64 + ((c1 ^ (s_ & 7)) << 3)];
        ((f16x2*)d0)[0] = p0; ((f16x2*)d0)[1] = p1;
        ((f16x2*)d0)[2] = p2; ((f16x2*)d0)[3] = p3;
        ((f16x2*)d1)[0] = p4; ((f16x2*)d1)[1] = p5;
        ((f16x2*)d1)[2] = p6; ((f16x2*)d1)[3] = p7;
    }
    __syncthreads();

    // ---- Y^T = V^T · P^T : wave owns 16 src nodes; 8 MFMAs (A from regs) ----
    f32x4 acc[4];
    #pragma unroll
    for (int i = 0; i < 4; ++i) acc[i] = 0.f;
    const int srow = wave * 16 + fr;
    #pragma unroll
    for (int kk = 0; kk < 2; ++kk) {
        int g = kk * 4 + qtr;
        f16x8 fb = *(const f16x8*)&sQ[srow * 64 + ((g ^ (srow & 7)) << 3)];
        #pragma unroll
        for (int mi = 0; mi < 4; ++mi)
            acc[mi] = __builtin_amdgcn_mfma_f32_16x16x32_f16(vf[kk][mi], fb, acc[mi], 0, 0, 0);
    }

    // ---- store: col = src node, row = dim ----
    const int node = wave * 16 + fr;
    const int fq = qtr * 4;
    u16* yh = Yh + ((size_t)bt * NNODE + node) * D_ + h * 64;
    #pragma unroll
    for (int mi = 0; mi < 4; ++mi) {
        ushort4 v = make_ushort4(f2h(acc[mi][0]), f2h(acc[mi][1]),
                                 f2h(acc[mi][2]), f2h(acc[mi][3]));
        *(ushort4*)&yh[mi * 16 + fq] = v;
    }
}

// ---------------------------------------------------------------------------
extern "C" void kernel_launch(void* const* d_in, const int* in_sizes, int n_in,
                              void* d_out, int out_size, void* d_ws, size_t ws_size,
                              hipStream_t stream)
{
    const float* H     = (const float*)d_in[0];
    const float* W_lin = (const float*)d_in[1];
    const float* W_val = (const float*)d_in[2];
    const float* a     = (const float*)d_in[3];
    const float* W_out = (const float*)d_in[4];
    const float* A0    = (const float*)d_in[5];
    const int*   src   = (const int*)d_in[6];
    const int*   dst   = (const int*)d_in[7];

    const size_t nX = (size_t)BTN * D_;              // 16777216 elems
    // ws layout: Hh [0,32M) | Xqh [32M,64M) | W's + gedge [64M, ~64.5M)
    u16* Hh  = (u16*)d_ws;
    u16* Xqh = Hh + nX;
    u16* Wlh   = Xqh + nX;
    u16* Wvh   = Wlh + D_ * D_;
    u16* Wouth = Wvh + D_ * D_;
    int2* gedge = (int2*)(Wouth + D_ * D_);
    u16* Yh = Hh;                                    // alias: Hh dead after GEMM2
    if (ws_size < (size_t)134217728) return;

    u16* Xvt = (u16*)d_out;                          // d_out scratch until GEMM3

    build_edge<<<1, 512, 0, stream>>>(src, dst, A0, gedge);
    prep_hi<<<4096, 256, 0, stream>>>(H, Hh, (int)(nX / 4));
    prep_w3<<<192, 256, 0, stream>>>(W_lin, W_val, W_out, Wlh, Wvh, Wouth);

    gemm_1p<3><<<1024, 256, 0, stream>>>(Hh, Wlh, Xqh);   // Q fp16 slices (swz)
    gemm_1p<2><<<1024, 256, 0, stream>>>(Hh, Wvh, Xvt);   // V^T fp16 slices

    fused_edge_agg<<<4096, 256, 0, stream>>>(Xqh, Xvt, gedge, a, Yh);

    gemm_1p<0><<<1024, 256, 0, stream>>>(Yh, Wouth, (float*)d_out);
}

// Round 14
// 104.481 us; speedup vs baseline: 2.3582x; 1.1516x over previous
//
#include <hip/hip_runtime.h>
#include <math.h>

#define D_    256
#define NE    512
#define NNODE 64
#define NHEAD 4
#define SLOPE 0.2f
#define BTN   65536

typedef __attribute__((ext_vector_type(4))) float f32x4;
typedef __attribute__((ext_vector_type(8))) _Float16 f16x8;
typedef __attribute__((ext_vector_type(2))) _Float16 f16x2;
typedef __attribute__((ext_vector_type(2))) __fp16   h16x2;   // builtin interop
typedef unsigned short u16;

__device__ inline u16 f2h(float x) {
    union { _Float16 h; u16 u; } v; v.h = (_Float16)x; return v.u;
}
__device__ inline f16x2 pkrtz(float lo, float hi) {
    h16x2 r = __builtin_amdgcn_cvt_pkrtz(lo, hi);
    f16x2 o; __builtin_memcpy(&o, &r, 4); return o;
}

#define GLD16(g, l) __builtin_amdgcn_global_load_lds( \
    (const __attribute__((address_space(1))) void*)(g), \
    (__attribute__((address_space(3))) void*)(l), 16, 0, 0)

// ---------------------------------------------------------------------------
// Edge table: pack (src<<8)|dst and log(A0+eps) into one int2. One block.
// ---------------------------------------------------------------------------
__global__ __launch_bounds__(512) void build_edge(const int* __restrict__ src,
    const int* __restrict__ dst, const float* __restrict__ A0,
    int2* __restrict__ gedge)
{
    const int t = threadIdx.x;
    int s = src[t], d = dst[t];
    float lg = logf(A0[s * NNODE + d] + 1e-8f);
    gedge[t] = make_int2((s << 8) | d, __float_as_int(lg));
}

// Three 256x256 weights -> fp16 in one launch (192 blocks).
__global__ __launch_bounds__(256) void prep_w3(const float* __restrict__ w0,
    const float* __restrict__ w1, const float* __restrict__ w2,
    u16* __restrict__ h0, u16* __restrict__ h1, u16* __restrict__ h2)
{
    int sel = blockIdx.x >> 6, b = blockIdx.x & 63;
    const float* s = sel == 0 ? w0 : sel == 1 ? w1 : w2;
    u16* h = sel == 0 ? h0 : sel == 1 ? h1 : h2;
    int i = b * 256 + threadIdx.x;
    float4 v = ((const float4*)s)[i];
    ((ushort4*)h)[i] = make_ushort4(f2h(v.x), f2h(v.y), f2h(v.z), f2h(v.w));
}

// ---------------------------------------------------------------------------
// Fused GEMM1+2: [Xq|Xv] = H(fp32) x [W_lin|W_val]^T(fp16, 512 rows).
// A: reg-staged fp32->fp16 (RTN), LDS stride 40 (~2-way banks).
// B: GLD16 linear. 128x128 tile, BK=32, 2048 blocks (512 m x 4 n).
// Epilogue: n-quadrant 0,1 -> Q slices [node][dim] chunk^=(node&7);
//           n-quadrant 2,3 -> V^T slices [dim][node] chunk^=(dim&7).
// ---------------------------------------------------------------------------
__global__ __launch_bounds__(256) void gemm12(const float* __restrict__ A32,
    const u16* __restrict__ B, u16* __restrict__ Xqh, u16* __restrict__ Xvt)
{
    __shared__ u16 sA[128 * 40];                     // padded stride 40
    __shared__ u16 sB[4096];                         // [128][32] linear
    __shared__ u16 sT[16384];                        // 4 waves x 8KB bounce
    const int t = threadIdx.x, lane = t & 63, wave = t >> 6;
    const int wm = wave >> 1, wn = wave & 1;
    const int bid = blockIdx.x;
    const int swz = (bid & 7) * 256 + (bid >> 3);    // XCD-contiguous, bijective
    const int m0 = (swz >> 2) * 128, nq = swz & 3, n0 = nq * 128;
    const int fr = lane & 15, kq = (lane >> 4) * 8;

    f32x4 acc[4][4];
    #pragma unroll
    for (int i = 0; i < 4; ++i)
        #pragma unroll
        for (int j = 0; j < 4; ++j) acc[i][j] = 0.f;

    for (int k0 = 0; k0 < D_; k0 += 32) {
        // ---- A: 128x32 fp32 -> fp16 reg-staged ----
        #pragma unroll
        for (int rr = 0; rr < 2; ++rr) {
            int idx = rr * 256 + t;
            int row = idx >> 2, c8 = (idx & 3) * 8;
            const float* ap = A32 + (size_t)(m0 + row) * D_ + k0 + c8;
            float4 v0 = *(const float4*)ap;
            float4 v1 = *(const float4*)(ap + 4);
            f16x8 hv;
            hv[0] = (_Float16)v0.x; hv[1] = (_Float16)v0.y;
            hv[2] = (_Float16)v0.z; hv[3] = (_Float16)v0.w;
            hv[4] = (_Float16)v1.x; hv[5] = (_Float16)v1.y;
            hv[6] = (_Float16)v1.z; hv[7] = (_Float16)v1.w;
            *(f16x8*)&sA[row * 40 + c8] = hv;
        }
        // ---- B: GLD16, 512 chunks over 2 rounds ----
        #pragma unroll
        for (int s = 0; s < 2; ++s) {
            const int cb = (s * 4 + wave) * 64;
            const int c  = cb + lane;
            const int row = c >> 2, ks = (c & 3) * 8;
            GLD16(B + (size_t)(n0 + row) * D_ + k0 + ks, sB + cb * 8);
        }
        __syncthreads();

        f16x8 fa[4];
        #pragma unroll
        for (int mi = 0; mi < 4; ++mi)
            fa[mi] = *(const f16x8*)(sA + (wm * 64 + mi * 16 + fr) * 40 + kq);
        #pragma unroll
        for (int ni = 0; ni < 4; ++ni) {
            f16x8 fb = *(const f16x8*)(sB + (wn * 64 + ni * 16 + fr) * 32 + kq);
            #pragma unroll
            for (int mi = 0; mi < 4; ++mi)
                acc[mi][ni] = __builtin_amdgcn_mfma_f32_16x16x32_f16(fa[mi], fb, acc[mi][ni], 0, 0, 0);
        }
        __syncthreads();
    }

    // ---- epilogue: wave quadrant = one (bt,h) 64x64 slice ----
    const int fq = (lane >> 4) * 4;   // C/D: col = lane&15, row = (lane>>4)*4 + reg
    u16* wT = sT + wave * 4096;
    const bool isQ = nq < 2;
    #pragma unroll
    for (int mi = 0; mi < 4; ++mi)
        #pragma unroll
        for (int ni = 0; ni < 4; ++ni) {
            int node0 = mi * 16 + fq;              // r = 0..3 consecutive nodes
            int dim   = ni * 16 + fr;
            if (!isQ) {                            // V^T: [dim][node], chunk^=dim&7
                ushort4 v = make_ushort4(f2h(acc[mi][ni][0]), f2h(acc[mi][ni][1]),
                                         f2h(acc[mi][ni][2]), f2h(acc[mi][ni][3]));
                *(ushort4*)&wT[dim * 64 + (((node0 >> 3) ^ (dim & 7)) << 3) + (node0 & 7)] = v;
            } else {                               // Q: [node][dim], chunk^=node&7
                #pragma unroll
                for (int r = 0; r < 4; ++r) {
                    int node = node0 + r;
                    wT[node * 64 + ((((dim >> 3) ^ (node & 7))) << 3) + (dim & 7)]
                        = f2h(acc[mi][ni][r]);
                }
            }
        }
    __syncthreads();
    const int btq = (m0 >> 6) + wm;
    const int hq  = isQ ? (n0 >> 6) + wn : ((n0 - 256) >> 6) + wn;
    u16* gx = (isQ ? Xqh : Xvt) + ((size_t)btq * NHEAD + hq) * 4096;
    #pragma unroll
    for (int r = 0; r < 8; ++r)
        *(f16x8*)&gx[r * 512 + lane * 8] = *(const f16x8*)&wT[r * 512 + lane * 8];
}

// ---------------------------------------------------------------------------
// GEMM3: out = Yh(fp16) x W_out^T(fp16), fp32 row-major out. GLD16 staging.
// ---------------------------------------------------------------------------
__global__ __launch_bounds__(256) void gemm3(const u16* __restrict__ A,
    const u16* __restrict__ B, float* __restrict__ Cout)
{
    __shared__ u16 sA[4096], sB[4096];
    const int t = threadIdx.x, lane = t & 63, wave = t >> 6;
    const int wm = wave >> 1, wn = wave & 1;
    const int bid = blockIdx.x;
    const int swz = (bid & 7) * 128 + (bid >> 3);
    const int m0 = (swz >> 1) * 128, n0 = (swz & 1) * 128;
    const int fr = lane & 15, kq = (lane >> 4) * 8;

    f32x4 acc[4][4];
    #pragma unroll
    for (int i = 0; i < 4; ++i)
        #pragma unroll
        for (int j = 0; j < 4; ++j) acc[i][j] = 0.f;

    for (int k0 = 0; k0 < D_; k0 += 32) {
        #pragma unroll
        for (int s = 0; s < 2; ++s) {
            const int cb = (s * 4 + wave) * 64;
            const int c  = cb + lane;
            const int row = c >> 2, ks = (c & 3) * 8;
            GLD16(A + (size_t)(m0 + row) * D_ + k0 + ks, sA + cb * 8);
            GLD16(B + (size_t)(n0 + row) * D_ + k0 + ks, sB + cb * 8);
        }
        __syncthreads();

        f16x8 fa[4];
        #pragma unroll
        for (int mi = 0; mi < 4; ++mi)
            fa[mi] = *(const f16x8*)(sA + (wm * 64 + mi * 16 + fr) * 32 + kq);
        #pragma unroll
        for (int ni = 0; ni < 4; ++ni) {
            f16x8 fb = *(const f16x8*)(sB + (wn * 64 + ni * 16 + fr) * 32 + kq);
            #pragma unroll
            for (int mi = 0; mi < 4; ++mi)
                acc[mi][ni] = __builtin_amdgcn_mfma_f32_16x16x32_f16(fa[mi], fb, acc[mi][ni], 0, 0, 0);
        }
        __syncthreads();
    }

    const int fq = (lane >> 4) * 4;
    #pragma unroll
    for (int mi = 0; mi < 4; ++mi)
        #pragma unroll
        for (int ni = 0; ni < 4; ++ni)
            #pragma unroll
            for (int r = 0; r < 4; ++r) {
                int m = m0 + wm * 64 + mi * 16 + fq + r;
                int n = n0 + wn * 64 + ni * 16 + fr;
                Cout[(size_t)m * D_ + n] = acc[mi][ni][r];
            }
}

// ---------------------------------------------------------------------------
// Fused edge scores + softmax + aggregation, one block per (bt, head).
// (unchanged from round 13: MFMA edge scores, hoisted linear term,
//  edge-parallel atomics, MFMA aggregation; LDS ~28.9KB)
// ---------------------------------------------------------------------------
__global__ __launch_bounds__(256, 5) void fused_edge_agg(
    const u16* __restrict__ Xqh, const u16* __restrict__ Xvt,
    const int2* __restrict__ gedge, const float* __restrict__ a,
    u16* __restrict__ Yh)
{
    __shared__ u16   sQ[4096];    // 8 KB  Q fp16 swizzled; later P fp16 (swz)
    __shared__ float sP[4096];    // 16 KB P f32 [src][dst]
    __shared__ float sBn[NNODE];  // b[n] = <q_n, a>
    __shared__ float sLin[NE];    // 0.6*(b_s+b_d) + logA0
    __shared__ int   sPack[NE];   // (src<<8)|dst

    const int t = threadIdx.x, lane = t & 63, wave = t >> 6;
    const int fr = lane & 15, qtr = lane >> 4;
    const int bt = blockIdx.x >> 2, h = blockIdx.x & 3;

    // ---- V^T fragments: direct global -> register (chunk ^= dim&7 baked) ----
    const u16* gv = Xvt + ((size_t)bt * NHEAD + h) * 4096;
    f16x8 vf[2][4];
    #pragma unroll
    for (int kk = 0; kk < 2; ++kk) {
        int g = kk * 4 + qtr;
        #pragma unroll
        for (int mi = 0; mi < 4; ++mi) {
            int arow = mi * 16 + fr;
            vf[kk][mi] = *(const f16x8*)&gv[arow * 64 + ((g ^ (arow & 7)) << 3)];
        }
    }
    // ---- B-fragments for the score MFMA: 0.4*a, replicated rows ----
    f16x8 af[2];
    #pragma unroll
    for (int kk = 0; kk < 2; ++kk) {
        const float* ab = a + h * 64 + kk * 32 + qtr * 8;
        float4 a0 = *(const float4*)ab, a1 = *(const float4*)(ab + 4);
        af[kk][0] = (_Float16)(0.4f * a0.x); af[kk][1] = (_Float16)(0.4f * a0.y);
        af[kk][2] = (_Float16)(0.4f * a0.z); af[kk][3] = (_Float16)(0.4f * a0.w);
        af[kk][4] = (_Float16)(0.4f * a1.x); af[kk][5] = (_Float16)(0.4f * a1.y);
        af[kk][6] = (_Float16)(0.4f * a1.z); af[kk][7] = (_Float16)(0.4f * a1.w);
    }

    // ---- stage Q (already swizzled in global); zero P ----
    const u16* gq = Xqh + ((size_t)bt * NHEAD + h) * 4096;
    #pragma unroll
    for (int r = 0; r < 2; ++r) {
        int id = r * 256 + t;
        GLD16(gq + id * 8, (char*)sQ + id * 16);
    }
    #pragma unroll
    for (int i = 0; i < 4; ++i)
        ((float4*)sP)[t + i * 256] = make_float4(0.f, 0.f, 0.f, 0.f);
    __syncthreads();

    // ---- b[n] = <q_n, a>: 4 threads per node, 16 dims each (swizzled read) ----
    {
        int n = t >> 2, qq = t & 3;
        float b = 0.f;
        #pragma unroll
        for (int j = 0; j < 2; ++j) {
            int ck = qq * 2 + j;
            f16x8 qv = *(const f16x8*)&sQ[n * 64 + ((ck ^ (n & 7)) << 3)];
            const float* ab = a + h * 64 + ck * 8;
            float4 a0 = *(const float4*)ab, a1 = *(const float4*)(ab + 4);
            b = fmaf((float)qv[0], a0.x, b); b = fmaf((float)qv[1], a0.y, b);
            b = fmaf((float)qv[2], a0.z, b); b = fmaf((float)qv[3], a0.w, b);
            b = fmaf((float)qv[4], a1.x, b); b = fmaf((float)qv[5], a1.y, b);
            b = fmaf((float)qv[6], a1.z, b); b = fmaf((float)qv[7], a1.w, b);
        }
        b += __shfl_xor(b, 1);
        b += __shfl_xor(b, 2);
        if (qq == 0) sBn[n] = b;
    }
    __syncthreads();

    // ---- edge tables: sPack + hoisted linear term ----
    #pragma unroll
    for (int i = 0; i < 2; ++i) {
        int e = t + i * 256;
        int2 ge = gedge[e];
        int s_ = ge.x >> 8, d_ = ge.x & 255;
        sPack[e] = ge.x;
        sLin[e] = 0.6f * (sBn[s_] + sBn[d_]) + __int_as_float(ge.y);
    }
    __syncthreads();

    // ---- edge pass: 8 tiles/wave x 16 edges, scores via MFMA ----
    const int wbase = wave * 128;
    #pragma unroll
    for (int tt = 0; tt < 8; ++tt) {
        int e = wbase + tt * 16 + fr;
        int pk = sPack[e];
        int s_ = pk >> 8, d_ = pk & 255;
        f32x4 acc = 0.f;
        #pragma unroll
        for (int kk = 0; kk < 2; ++kk) {
            int ck = kk * 4 + qtr;
            f16x8 qs = *(const f16x8*)&sQ[s_ * 64 + ((ck ^ (s_ & 7)) << 3)];
            f16x8 qd = *(const f16x8*)&sQ[d_ * 64 + ((ck ^ (d_ & 7)) << 3)];
            f16x8 x = qs + qd;                       // 4x v_pk_add_f16
            unsigned xu[4];
            __builtin_memcpy(xu, &x, 16);
            xu[0] &= 0x7FFF7FFFu; xu[1] &= 0x7FFF7FFFu;
            xu[2] &= 0x7FFF7FFFu; xu[3] &= 0x7FFF7FFFu;
            f16x8 xa;
            __builtin_memcpy(&xa, xu, 16);
            acc = __builtin_amdgcn_mfma_f32_16x16x32_f16(xa, af[kk], acc, 0, 0, 0);
        }
        int c = lane & 15;
        if (c < 4) {
            float av = c == 0 ? acc[0] : c == 1 ? acc[1] : c == 2 ? acc[2] : acc[3];
            int eg = wbase + tt * 16 + qtr * 4 + c;
            int pk2 = sPack[eg];
            atomicAdd(&sP[(pk2 >> 8) * 64 + (pk2 & 255)], __expf(av + sLin[eg]));
        }
    }
    __syncthreads();

    // ---- convert: row-sum -> denom; normalize; fp16 into dead Q (swizzled) ----
    {
        int s_ = t >> 2, qq = t & 3;
        const float4* row = (const float4*)&sP[s_ * 64 + qq * 16];
        float4 v0 = row[0], v1 = row[1], v2 = row[2], v3 = row[3];
        float part = v0.x + v0.y + v0.z + v0.w + v1.x + v1.y + v1.z + v1.w
                   + v2.x + v2.y + v2.z + v2.w + v3.x + v3.y + v3.z + v3.w;
        part += __shfl_xor(part, 1);
        part += __shfl_xor(part, 2);
        float inv = part > 0.f ? 1.f / part : 0.f;
        f16x2 p0 = pkrtz(v0.x * inv, v0.y * inv), p1 = pkrtz(v0.z * inv, v0.w * inv);
        f16x2 p2 = pkrtz(v1.x * inv, v1.y * inv), p3 = pkrtz(v1.z * inv, v1.w * inv);
        f16x2 p4 = pkrtz(v2.x * inv, v2.y * inv), p5 = pkrtz(v2.z * inv, v2.w * inv);
        f16x2 p6 = pkrtz(v3.x * inv, v3.y * inv), p7 = pkrtz(v3.z * inv, v3.w * inv);
        int c0 = qq * 2, c1 = qq * 2 + 1;
        u16* d0 = &sQ[s_ * 64 + ((c0 ^ (s_ & 7)) << 3)];
        u16* d1 = &sQ[s_ * 64 + ((c1 ^ (s_ & 7)) << 3)];
        ((f16x2*)d0)[0] = p0; ((f16x2*)d0)[1] = p1;
        ((f16x2*)d0)[2] = p2; ((f16x2*)d0)[3] = p3;
        ((f16x2*)d1)[0] = p4; ((f16x2*)d1)[1] = p5;
        ((f16x2*)d1)[2] = p6; ((f16x2*)d1)[3] = p7;
    }
    __syncthreads();

    // ---- Y^T = V^T · P^T : wave owns 16 src nodes; 8 MFMAs (A from regs) ----
    f32x4 acc[4];
    #pragma unroll
    for (int i = 0; i < 4; ++i) acc[i] = 0.f;
    const int srow = wave * 16 + fr;
    #pragma unroll
    for (int kk = 0; kk < 2; ++kk) {
        int g = kk * 4 + qtr;
        f16x8 fb = *(const f16x8*)&sQ[srow * 64 + ((g ^ (srow & 7)) << 3)];
        #pragma unroll
        for (int mi = 0; mi < 4; ++mi)
            acc[mi] = __builtin_amdgcn_mfma_f32_16x16x32_f16(vf[kk][mi], fb, acc[mi], 0, 0, 0);
    }

    // ---- store: col = src node, row = dim ----
    const int node = wave * 16 + fr;
    const int fq = qtr * 4;
    u16* yh = Yh + ((size_t)bt * NNODE + node) * D_ + h * 64;
    #pragma unroll
    for (int mi = 0; mi < 4; ++mi) {
        ushort4 v = make_ushort4(f2h(acc[mi][0]), f2h(acc[mi][1]),
                                 f2h(acc[mi][2]), f2h(acc[mi][3]));
        *(ushort4*)&yh[mi * 16 + fq] = v;
    }
}

// ---------------------------------------------------------------------------
extern "C" void kernel_launch(void* const* d_in, const int* in_sizes, int n_in,
                              void* d_out, int out_size, void* d_ws, size_t ws_size,
                              hipStream_t stream)
{
    const float* H     = (const float*)d_in[0];
    const float* W_lin = (const float*)d_in[1];
    const float* W_val = (const float*)d_in[2];
    const float* a     = (const float*)d_in[3];
    const float* W_out = (const float*)d_in[4];
    const float* A0    = (const float*)d_in[5];
    const int*   src   = (const int*)d_in[6];
    const int*   dst   = (const int*)d_in[7];

    const size_t nX = (size_t)BTN * D_;              // 16777216 elems
    // ws layout: Xqh [0,32M) | Yh [32M,64M) | Wqv 256K | Wout 128K | gedge
    u16*  Xqh   = (u16*)d_ws;
    u16*  Yh    = Xqh + nX;
    u16*  Wqv   = Yh + nX;                           // 512 x 256 fp16
    u16*  Wouth = Wqv + 512 * D_;
    int2* gedge = (int2*)(Wouth + D_ * D_);
    if (ws_size < (size_t)134217728) return;

    u16* Xvt = (u16*)d_out;                          // d_out scratch until gemm3

    build_edge<<<1, 512, 0, stream>>>(src, dst, A0, gedge);
    prep_w3<<<192, 256, 0, stream>>>(W_lin, W_val, W_out,
                                     Wqv, Wqv + D_ * D_, Wouth);

    gemm12<<<2048, 256, 0, stream>>>(H, Wqv, Xqh, Xvt);

    fused_edge_agg<<<4096, 256, 0, stream>>>(Xqh, Xvt, gedge, a, Yh);

    gemm3<<<1024, 256, 0, stream>>>(Yh, Wouth, (float*)d_out);
}